// Round 4
// baseline (3451.541 us; speedup 1.0000x reference)
//
#include <hip/hip_runtime.h>
#include <stdint.h>

#define TOK 2048
#define HID 4096
#define VOC 32000
#define NKT (HID / 64)  // 64 K-tiles of BK=64

typedef __attribute__((ext_vector_type(4))) float f32x4;
typedef __attribute__((ext_vector_type(8))) short bf16x8;
typedef __attribute__((ext_vector_type(8))) unsigned short u16x8;

__device__ __forceinline__ float bf2f(unsigned short u) {
  return __uint_as_float(((unsigned int)u) << 16);
}
__device__ __forceinline__ unsigned short f2bf(float f) {
  unsigned int u = __float_as_uint(f);
  u += 0x7FFFu + ((u >> 16) & 1u);  // round-to-nearest-even
  return (unsigned short)(u >> 16);
}
// packed f32x2 -> bf16x2 (RNE), dst.lo = a, dst.hi = b
__device__ __forceinline__ unsigned int cvt2(float a, float b) {
  unsigned int r;
  asm volatile("v_cvt_pk_bf16_f32 %0, %1, %2" : "=v"(r) : "v"(a), "v"(b));
  return r;
}

// ---------------- cast f32 -> bf16 (inputs only; weights converted in-GEMM) ----------------
__global__ __launch_bounds__(256) void cast_f32_bf16(const float* __restrict__ in,
                                                     unsigned short* __restrict__ out,
                                                     long n) {
  long i = ((long)blockIdx.x * 256 + threadIdx.x) * 4;
  const long stride = (long)gridDim.x * 256 * 4;
  for (; i < n; i += stride) {
    const float4 v = *(const float4*)(in + i);
    ushort4 o;
    o.x = f2bf(v.x); o.y = f2bf(v.y); o.z = f2bf(v.z); o.w = f2bf(v.w);
    *(ushort4*)(out + i) = o;
  }
}

// ---------------- async global -> LDS (16B/lane) ----------------
__device__ __forceinline__ void gload_lds16(const void* g, void* l) {
  __builtin_amdgcn_global_load_lds(
      (const __attribute__((address_space(1))) unsigned int*)(uintptr_t)g,
      (__attribute__((address_space(3))) unsigned int*)(uintptr_t)l,
      16, 0, 0);
}

// ---------------- 256x256 bf16 GEMM with fused f32->bf16 B staging ----------------
// C[M,N] = A[M,K] * Bf[N,K]^T, A bf16 (pre-cast), Bf float32 (converted in-kernel).
// 8 waves (2M x 4N), BK=64, LDS 2dbuf x 2half x [128][64] for A and B (128 KiB).
// Swizzle: byte ^= ((row&7)<<4). A: pre-swizzled global source + gload_lds linear.
// B: reg-stage f32 -> v_cvt_pk_bf16_f32 -> swizzled ds_write_b128.
// vmcnt ledger/tile: enter A(u+1):4 -> +B32(u+1):8 -> lgkm0+bar -> +A(u+2):4 ->
// q01 -> vmcnt(4) [retire A(u+1)+B32, keep A(u+2)] -> writeB -> lgkm0+bar.
__global__ __launch_bounds__(512, 2) void gemm256f(const unsigned short* __restrict__ A,
                                                   const float* __restrict__ Bf,
                                                   unsigned short* __restrict__ C) {
  __shared__ unsigned short As[2][2][128 * 64];
  __shared__ unsigned short Bs[2][2][128 * 64];
  const int tid = threadIdx.x;
  const int w = tid >> 6;
  const int l = tid & 63;
  const int wr = w >> 2;   // 0..1 (M half)
  const int wc = w & 3;    // 0..3 (N quarter)

  // T1: XCD-aware swizzle. grid = 1000 blocks, 1000 % 8 == 0.
  const int bid = blockIdx.x;
  const int cpx = gridDim.x >> 3;                 // 125
  const int swz = (bid & 7) * cpx + (bid >> 3);
  const int mt = swz & 7;                         // 8 M-tiles
  const int nt = swz >> 3;                        // 125 N-tiles

  const size_t Abase = (size_t)mt * 256 * HID;

  f32x4 acc[8][4] = {};

  // ---- A staging (gload_lds, pre-swizzled source) ----
  const int r8 = l >> 3;
  const int scol = ((l & 7) ^ r8) << 3;  // swizzled source column (elements)
  auto stageA = [&](int half, int v) {
    const unsigned short* src = A + Abase + (size_t)half * 128 * HID + (size_t)v * 64 + scol;
#pragma unroll
    for (int i = 0; i < 2; ++i) {
      const int c = 2 * w + i;
      gload_lds16(src + (size_t)(c * 8 + r8) * HID, &As[v & 1][half][c * 512]);
    }
  };

  // ---- B staging (f32 global -> regs -> cvt -> swizzled ds_write) ----
  // thread t: logical B-tile row rB = t>>1 (0..255), cols (t&1)*32 .. +31 (f32)
  const int rB = tid >> 1;
  const int rhalf = rB >> 7;
  const int rrow = rB & 127;
  const int swzB = (rB & 7) << 4;
  const int tcol = (tid & 1) << 6;  // byte col base (bit 6) — XORed with swzB
  const float* bsrc = Bf + (size_t)(nt * 256 + rB) * HID + (tid & 1) * 32;

  auto loadB = [&](int v, float4* Lb) {
#pragma unroll
    for (int j = 0; j < 8; ++j)
      Lb[j] = *(const float4*)(bsrc + (size_t)v * 64 + j * 4);
  };
  auto writeB = [&](int v, const float4* Lb) {
    char* dst = (char*)&Bs[v & 1][rhalf][0] + (rrow << 7);
#pragma unroll
    for (int g = 0; g < 4; ++g) {
      uint4 wv;
      wv.x = cvt2(Lb[2 * g].x, Lb[2 * g].y);
      wv.y = cvt2(Lb[2 * g].z, Lb[2 * g].w);
      wv.z = cvt2(Lb[2 * g + 1].x, Lb[2 * g + 1].y);
      wv.w = cvt2(Lb[2 * g + 1].z, Lb[2 * g + 1].w);
      *(uint4*)(dst + ((tcol | (16 * g)) ^ swzB)) = wv;
    }
  };

  // ---- prologue: B(0) via regs; A(0),A(1) via gload_lds ----
  {
    float4 Lb[8];
    loadB(0, Lb);                       // 8 vm
    stageA(0, 0); stageA(1, 0);         // +4 = 12
    stageA(0, 1); stageA(1, 1);         // +4 = 16
    asm volatile("s_waitcnt vmcnt(8)" ::: "memory");   // retire B32(0), keep A(0),A(1)
    writeB(0, Lb);
    asm volatile("s_waitcnt vmcnt(4)" ::: "memory");   // retire A(0), keep A(1)
    asm volatile("s_waitcnt lgkmcnt(0)" ::: "memory"); // drain own ds_writes
    __builtin_amdgcn_s_barrier();
  }

  const int lr = l & 15;
  const int c0 = ((l >> 4) << 4) ^ ((lr & 7) << 4);  // byte col for kk=0
  const int c1 = c0 ^ 64;                            // byte col for kk=32
  const int brow = (wc & 1) * 64;                    // wave's N-row base in its B half

#pragma unroll 2
  for (int u = 0; u < NKT; ++u) {
    const int cur = u & 1;
    const char* Ah = (const char*)&As[cur][wr][0];
    const char* Bh = (const char*)&Bs[cur][wc >> 1][0];
    bf16x8 a0[8], a1[8], b0[4], b1[4];
    float4 Lb[8];

    // ---- issue all 24 ds_reads ----
#pragma unroll
    for (int mf = 0; mf < 4; ++mf) {
      const int rb = (mf * 16 + lr) << 7;
      a0[2 * mf]     = *(const bf16x8*)(Ah + rb + c0);
      a0[2 * mf + 1] = *(const bf16x8*)(Ah + rb + c1);
    }
#pragma unroll
    for (int nf = 0; nf < 2; ++nf) {
      const int rb = (brow + nf * 16 + lr) << 7;
      b0[2 * nf]     = *(const bf16x8*)(Bh + rb + c0);
      b0[2 * nf + 1] = *(const bf16x8*)(Bh + rb + c1);
    }
#pragma unroll
    for (int mf = 0; mf < 4; ++mf) {
      const int rb = ((mf + 4) * 16 + lr) << 7;
      a1[2 * mf]     = *(const bf16x8*)(Ah + rb + c0);
      a1[2 * mf + 1] = *(const bf16x8*)(Ah + rb + c1);
    }
#pragma unroll
    for (int nf = 0; nf < 2; ++nf) {
      const int rb = (brow + (nf + 2) * 16 + lr) << 7;
      b1[2 * nf]     = *(const bf16x8*)(Bh + rb + c0);
      b1[2 * nf + 1] = *(const bf16x8*)(Bh + rb + c1);
    }

    __builtin_amdgcn_s_setprio(1);
    // q(0,0): a0 x b0
#pragma unroll
    for (int mf = 0; mf < 4; ++mf)
#pragma unroll
      for (int nf = 0; nf < 2; ++nf) {
        acc[mf][nf] = __builtin_amdgcn_mfma_f32_16x16x32_bf16(a0[2 * mf], b0[2 * nf], acc[mf][nf], 0, 0, 0);
        acc[mf][nf] = __builtin_amdgcn_mfma_f32_16x16x32_bf16(a0[2 * mf + 1], b0[2 * nf + 1], acc[mf][nf], 0, 0, 0);
      }
    // q(1,0): a1 x b0  (b0 dead after)
#pragma unroll
    for (int mf = 0; mf < 4; ++mf)
#pragma unroll
      for (int nf = 0; nf < 2; ++nf) {
        acc[4 + mf][nf] = __builtin_amdgcn_mfma_f32_16x16x32_bf16(a1[2 * mf], b0[2 * nf], acc[4 + mf][nf], 0, 0, 0);
        acc[4 + mf][nf] = __builtin_amdgcn_mfma_f32_16x16x32_bf16(a1[2 * mf + 1], b0[2 * nf + 1], acc[4 + mf][nf], 0, 0, 0);
      }

    // B32(u+1) loads — b0's registers just freed
    if (u + 1 < NKT) loadB(u + 1, Lb);

    // q(1,1): a1 x b1
#pragma unroll
    for (int mf = 0; mf < 4; ++mf)
#pragma unroll
      for (int nf = 0; nf < 2; ++nf) {
        acc[4 + mf][2 + nf] = __builtin_amdgcn_mfma_f32_16x16x32_bf16(a1[2 * mf], b1[2 * nf], acc[4 + mf][2 + nf], 0, 0, 0);
        acc[4 + mf][2 + nf] = __builtin_amdgcn_mfma_f32_16x16x32_bf16(a1[2 * mf + 1], b1[2 * nf + 1], acc[4 + mf][2 + nf], 0, 0, 0);
      }
    __builtin_amdgcn_s_setprio(0);

    // all reads of this tile's buffers drained before stageA(u+2) overwrites As[cur]
    if (u + 2 < NKT) {
      asm volatile("s_waitcnt lgkmcnt(0)" ::: "memory");
      __builtin_amdgcn_s_barrier();
      stageA(0, u + 2); stageA(1, u + 2);
    }

    __builtin_amdgcn_s_setprio(1);
    // q(0,1): register-only (a0, b1 held) — covers stage/convert shadow
#pragma unroll
    for (int mf = 0; mf < 4; ++mf)
#pragma unroll
      for (int nf = 0; nf < 2; ++nf) {
        acc[mf][2 + nf] = __builtin_amdgcn_mfma_f32_16x16x32_bf16(a0[2 * mf], b1[2 * nf], acc[mf][2 + nf], 0, 0, 0);
        acc[mf][2 + nf] = __builtin_amdgcn_mfma_f32_16x16x32_bf16(a0[2 * mf + 1], b1[2 * nf + 1], acc[mf][2 + nf], 0, 0, 0);
      }
    __builtin_amdgcn_s_setprio(0);

    if (u + 1 < NKT) {
      if (u + 2 < NKT) {
        asm volatile("s_waitcnt vmcnt(4)" ::: "memory");  // retire A(u+1)+B32(u+1), keep A(u+2)
      } else {
        asm volatile("s_waitcnt vmcnt(0)" ::: "memory");  // tail: no A(u+2) in flight
      }
      writeB(u + 1, Lb);
      asm volatile("s_waitcnt lgkmcnt(0)" ::: "memory");  // drain own ds_writes
      __builtin_amdgcn_s_barrier();
    }
  }

  // epilogue: D col = lane&15 (N), row = (lane>>4)*4 + reg (M)
  const int lg = (l >> 4) * 4;
#pragma unroll
  for (int mf = 0; mf < 8; ++mf)
#pragma unroll
    for (int nf = 0; nf < 4; ++nf)
#pragma unroll
      for (int r = 0; r < 4; ++r) {
        const int row = mt * 256 + wr * 128 + mf * 16 + lg + r;
        const int col = nt * 256 + wc * 64 + nf * 16 + lr;
        C[(size_t)row * VOC + col] = f2bf(acc[mf][nf][r]);
      }
}

// ---------------- per-token JSD ----------------
__device__ __forceinline__ void merge_ms(float& m, float& s, float om, float os) {
  float nm = fmaxf(m, om);
  s = s * __expf(m - nm) + os * __expf(om - nm);
  m = nm;
}

__global__ __launch_bounds__(256) void jsd_kernel(const unsigned short* __restrict__ SL,
                                                  const unsigned short* __restrict__ TL,
                                                  float* __restrict__ partials) {
  const int t = blockIdx.x;
  const int tid = threadIdx.x;
  const unsigned short* srow = SL + (size_t)t * VOC;
  const unsigned short* trow = TL + (size_t)t * VOC;

  float ms = -INFINITY, ss = 0.f, mt_ = -INFINITY, st = 0.f;
  for (int c = tid; c < VOC / 8; c += 256) {
    u16x8 vs = *(const u16x8*)(srow + c * 8);
    u16x8 vt = *(const u16x8*)(trow + c * 8);
    float zs[8], zt[8];
    float m8s = -INFINITY, m8t = -INFINITY;
#pragma unroll
    for (int j = 0; j < 8; ++j) {
      zs[j] = bf2f(vs[j]); zt[j] = bf2f(vt[j]);
      m8s = fmaxf(m8s, zs[j]); m8t = fmaxf(m8t, zt[j]);
    }
    float nms = fmaxf(ms, m8s);
    float es = 0.f;
#pragma unroll
    for (int j = 0; j < 8; ++j) es += __expf(zs[j] - nms);
    ss = ss * __expf(ms - nms) + es; ms = nms;
    float nmt = fmaxf(mt_, m8t);
    float et = 0.f;
#pragma unroll
    for (int j = 0; j < 8; ++j) et += __expf(zt[j] - nmt);
    st = st * __expf(mt_ - nmt) + et; mt_ = nmt;
  }
#pragma unroll
  for (int off = 32; off > 0; off >>= 1) {
    float om = __shfl_xor(ms, off), os = __shfl_xor(ss, off);
    merge_ms(ms, ss, om, os);
    float omt = __shfl_xor(mt_, off), ost = __shfl_xor(st, off);
    merge_ms(mt_, st, omt, ost);
  }
  __shared__ float red[4][4];
  const int w = tid >> 6;
  if ((tid & 63) == 0) { red[w][0] = ms; red[w][1] = ss; red[w][2] = mt_; red[w][3] = st; }
  __syncthreads();
  float Ms = red[0][0], Ss = red[0][1], Mt = red[0][2], St = red[0][3];
#pragma unroll
  for (int i = 1; i < 4; ++i) {
    merge_ms(Ms, Ss, red[i][0], red[i][1]);
    merge_ms(Mt, St, red[i][2], red[i][3]);
  }
  const float logZs = Ms + __logf(Ss);
  const float logZt = Mt + __logf(St);

  float acc = 0.f;
  for (int c = tid; c < VOC / 8; c += 256) {
    u16x8 vs = *(const u16x8*)(srow + c * 8);
    u16x8 vt = *(const u16x8*)(trow + c * 8);
#pragma unroll
    for (int j = 0; j < 8; ++j) {
      float lq = bf2f(vs[j]) - logZs;
      float lp = bf2f(vt[j]) - logZt;
      float mx = fmaxf(lp, lq), mn = fminf(lp, lq);
      float lm = mx + log1pf(__expf(mn - mx)) - 0.69314718f;
      acc += __expf(lp) * (lp - lm) + __expf(lq) * (lq - lm);
    }
  }
  acc *= 0.5f;
#pragma unroll
  for (int off = 32; off > 0; off >>= 1) acc += __shfl_xor(acc, off);
  __shared__ float red2[4];
  if ((tid & 63) == 0) red2[w] = acc;
  __syncthreads();
  if (tid == 0) partials[t] = red2[0] + red2[1] + red2[2] + red2[3];
}

__global__ __launch_bounds__(256) void final_reduce(const float* __restrict__ partials,
                                                    float* __restrict__ out) {
  float a = 0.f;
  for (int i = threadIdx.x; i < TOK; i += 256) a += partials[i];
#pragma unroll
  for (int off = 32; off > 0; off >>= 1) a += __shfl_xor(a, off);
  __shared__ float red[4];
  const int w = threadIdx.x >> 6;
  if ((threadIdx.x & 63) == 0) red[w] = a;
  __syncthreads();
  if (threadIdx.x == 0) out[0] = (red[0] + red[1] + red[2] + red[3]) * (1.0f / TOK);
}

// ---------------- launch ----------------
extern "C" void kernel_launch(void* const* d_in, const int* in_sizes, int n_in,
                              void* d_out, int out_size, void* d_ws, size_t ws_size,
                              hipStream_t stream) {
  const float* sIn = (const float*)d_in[0];
  const float* tIn = (const float*)d_in[1];
  const float* sW  = (const float*)d_in[2];
  const float* tW  = (const float*)d_in[3];
  float* out = (float*)d_out;

  unsigned short* ws = (unsigned short*)d_ws;
  unsigned short* sA  = ws;                        // 2048*4096 bf16
  unsigned short* tA  = sA  + (long)TOK * HID;     // 2048*4096
  unsigned short* sL  = tA  + (long)TOK * HID;     // 2048*32000
  unsigned short* tL  = sL  + (long)TOK * VOC;     // 2048*32000
  float* partials = (float*)(tL + (long)TOK * VOC);

  cast_f32_bf16<<<2048, 256, 0, stream>>>(sIn, sA, (long)TOK * HID);
  cast_f32_bf16<<<2048, 256, 0, stream>>>(tIn, tA, (long)TOK * HID);

  const int nblk = (TOK / 256) * (VOC / 256);  // 8 * 125 = 1000
  gemm256f<<<nblk, 512, 0, stream>>>(sA, sW, sL);
  gemm256f<<<nblk, 512, 0, stream>>>(tA, tW, tL);

  jsd_kernel<<<TOK, 256, 0, stream>>>(sL, tL, partials);
  final_reduce<<<1, 256, 0, stream>>>(partials, out);
}

// Round 5
// 1915.911 us; speedup vs baseline: 1.8015x; 1.8015x over previous
//
#include <hip/hip_runtime.h>
#include <stdint.h>

#define TOK 2048
#define HID 4096
#define VOC 32000
#define NKT (HID / 64)  // 64 K-tiles of BK=64

typedef __attribute__((ext_vector_type(4))) float f32x4;
typedef __attribute__((ext_vector_type(8))) short bf16x8;
typedef __attribute__((ext_vector_type(8))) unsigned short u16x8;

__device__ __forceinline__ float bf2f(unsigned short u) {
  return __uint_as_float(((unsigned int)u) << 16);
}
__device__ __forceinline__ unsigned short f2bf(float f) {
  unsigned int u = __float_as_uint(f);
  u += 0x7FFFu + ((u >> 16) & 1u);  // round-to-nearest-even
  return (unsigned short)(u >> 16);
}
// packed f32x2 -> bf16x2 (RNE), dst.lo = a, dst.hi = b
__device__ __forceinline__ unsigned int cvt2(float a, float b) {
  unsigned int r;
  asm volatile("v_cvt_pk_bf16_f32 %0, %1, %2" : "=v"(r) : "v"(a), "v"(b));
  return r;
}

// ---------------- cast f32 -> bf16 (inputs only; weights converted in-GEMM) ----------------
__global__ __launch_bounds__(256) void cast_f32_bf16(const float* __restrict__ in,
                                                     unsigned short* __restrict__ out,
                                                     long n) {
  long i = ((long)blockIdx.x * 256 + threadIdx.x) * 4;
  const long stride = (long)gridDim.x * 256 * 4;
  for (; i < n; i += stride) {
    const float4 v = *(const float4*)(in + i);
    ushort4 o;
    o.x = f2bf(v.x); o.y = f2bf(v.y); o.z = f2bf(v.z); o.w = f2bf(v.w);
    *(ushort4*)(out + i) = o;
  }
}

// ---------------- async global -> LDS (16B/lane) ----------------
__device__ __forceinline__ void gload_lds16(const void* g, void* l) {
  __builtin_amdgcn_global_load_lds(
      (const __attribute__((address_space(1))) unsigned int*)(uintptr_t)g,
      (__attribute__((address_space(3))) unsigned int*)(uintptr_t)l,
      16, 0, 0);
}

// ---------------- 256x256 bf16 GEMM with fused f32->bf16 B staging (low-pressure) ----------------
// C[M,N] = A[M,K] * Bf[N,K]^T, A bf16 (pre-cast), Bf float32 (converted in-kernel).
// 8 waves (2M x 4N), BK=64, LDS 2dbuf x 2half x [128][64] for A and B (128 KiB).
// Register discipline (round-4 spill fix): B staged in TWO 16-reg halves; quadrant
// order q00,q01 (a0 dies) -> a1 -> q10,q11. Peak arch-VGPR ~110 + acc 128.
// Per-tile: loadBh1 | ds b0,b1,a0 | q00,q01 | loadBh2, ds a1 | vmcnt(4) cvt+wr h1 |
// lgkm0+bar | stageA(u+2) | q10,q11 (reg-only) | vmcnt(4) cvt+wr h2 | lgkm0+bar.
__global__ __launch_bounds__(512, 2) void gemm256f(const unsigned short* __restrict__ A,
                                                   const float* __restrict__ Bf,
                                                   unsigned short* __restrict__ C) {
  __shared__ unsigned short As[2][2][128 * 64];
  __shared__ unsigned short Bs[2][2][128 * 64];
  const int tid = threadIdx.x;
  const int w = tid >> 6;
  const int l = tid & 63;
  const int wr = w >> 2;   // 0..1 (M half)
  const int wc = w & 3;    // 0..3 (N quarter)

  // T1: XCD-aware swizzle. grid = 1000 blocks, 1000 % 8 == 0.
  // Same-nt blocks are consecutive in swz -> co-located on one XCD (B-panel L2 reuse).
  const int bid = blockIdx.x;
  const int cpx = gridDim.x >> 3;                 // 125
  const int swz = (bid & 7) * cpx + (bid >> 3);
  const int mt = swz & 7;                         // 8 M-tiles
  const int nt = swz >> 3;                        // 125 N-tiles

  const size_t Abase = (size_t)mt * 256 * HID;

  f32x4 acc[8][4] = {};

  // ---- A staging (gload_lds, pre-swizzled source) ----
  const int r8 = l >> 3;
  const int scol = ((l & 7) ^ r8) << 3;  // swizzled source column (elements)
  auto stageA = [&](int half, int v) {
    const unsigned short* src = A + Abase + (size_t)half * 128 * HID + (size_t)v * 64 + scol;
#pragma unroll
    for (int i = 0; i < 2; ++i) {
      const int c = 2 * w + i;
      gload_lds16(src + (size_t)(c * 8 + r8) * HID, &As[v & 1][half][c * 512]);
    }
  };

  // ---- B staging (f32 global -> 16-reg half -> cvt -> swizzled ds_write) ----
  // thread t: logical B-tile row rB = t>>1 (0..255), cols (t&1)*32 .. +31 (f32)
  const int rB = tid >> 1;
  const int rhalf = rB >> 7;
  const int rrow = rB & 127;
  const int swzB = (rB & 7) << 4;
  const int tcol = (tid & 1) << 6;  // byte col base — XORed with swzB
  const float* bsrc = Bf + (size_t)(nt * 256 + rB) * HID + (tid & 1) * 32;

  auto loadBh = [&](int v, int h, float4* Lb) {
#pragma unroll
    for (int j = 0; j < 4; ++j)
      Lb[j] = *(const float4*)(bsrc + (size_t)v * 64 + (4 * h + j) * 4);
  };
  auto writeBh = [&](int v, int h, const float4* Lb) {
    char* dst = (char*)&Bs[v & 1][rhalf][0] + (rrow << 7);
#pragma unroll
    for (int g = 0; g < 2; ++g) {
      uint4 wv;
      wv.x = cvt2(Lb[2 * g].x, Lb[2 * g].y);
      wv.y = cvt2(Lb[2 * g].z, Lb[2 * g].w);
      wv.z = cvt2(Lb[2 * g + 1].x, Lb[2 * g + 1].y);
      wv.w = cvt2(Lb[2 * g + 1].z, Lb[2 * g + 1].w);
      *(uint4*)(dst + ((tcol | (16 * (2 * h + g))) ^ swzB)) = wv;
    }
  };

  // ---- prologue: B(0) both halves via regs; A(0),A(1) via gload_lds ----
  {
    float4 L1[4], L2[4];
    loadBh(0, 0, L1);                   // 4 vm
    loadBh(0, 1, L2);                   // 8
    stageA(0, 0); stageA(1, 0);         // 12
    stageA(0, 1); stageA(1, 1);         // 16
    asm volatile("s_waitcnt vmcnt(12)" ::: "memory");  // Bh1 done
    writeBh(0, 0, L1);
    asm volatile("s_waitcnt vmcnt(8)" ::: "memory");   // Bh2 done
    writeBh(0, 1, L2);
    asm volatile("s_waitcnt vmcnt(4)" ::: "memory");   // A(0) done, keep A(1)
    asm volatile("s_waitcnt lgkmcnt(0)" ::: "memory"); // drain own ds_writes
    __builtin_amdgcn_s_barrier();
  }

  const int lr = l & 15;
  const int c0 = ((l >> 4) << 4) ^ ((lr & 7) << 4);  // byte col for kk=0
  const int c1 = c0 ^ 64;                            // byte col for kk=32
  const int brow = (wc & 1) * 64;                    // wave's N-row base in its B half

#pragma unroll 2
  for (int u = 0; u < NKT; ++u) {
    const int cur = u & 1;
    const char* Ah = (const char*)&As[cur][wr][0];
    const char* Bh = (const char*)&Bs[cur][wc >> 1][0];
    bf16x8 a[8], b0[4], b1[4];
    float4 L1[4], L2[4];

    // issue next-tile B half-1 earliest (latency under q00/q01)
    if (u + 1 < NKT) loadBh(u + 1, 0, L1);

    // ds_reads: b0, b1, a0
#pragma unroll
    for (int nf = 0; nf < 2; ++nf) {
      const int rb = (brow + nf * 16 + lr) << 7;
      b0[2 * nf]     = *(const bf16x8*)(Bh + rb + c0);
      b0[2 * nf + 1] = *(const bf16x8*)(Bh + rb + c1);
    }
#pragma unroll
    for (int nf = 0; nf < 2; ++nf) {
      const int rb = (brow + (nf + 2) * 16 + lr) << 7;
      b1[2 * nf]     = *(const bf16x8*)(Bh + rb + c0);
      b1[2 * nf + 1] = *(const bf16x8*)(Bh + rb + c1);
    }
#pragma unroll
    for (int mf = 0; mf < 4; ++mf) {
      const int rb = (mf * 16 + lr) << 7;
      a[2 * mf]     = *(const bf16x8*)(Ah + rb + c0);
      a[2 * mf + 1] = *(const bf16x8*)(Ah + rb + c1);
    }

    __builtin_amdgcn_s_setprio(1);
    // q(0,0): a0 x b0 ; q(0,1): a0 x b1  -> a0 dies
#pragma unroll
    for (int mf = 0; mf < 4; ++mf)
#pragma unroll
      for (int nf = 0; nf < 2; ++nf) {
        acc[mf][nf] = __builtin_amdgcn_mfma_f32_16x16x32_bf16(a[2 * mf], b0[2 * nf], acc[mf][nf], 0, 0, 0);
        acc[mf][nf] = __builtin_amdgcn_mfma_f32_16x16x32_bf16(a[2 * mf + 1], b0[2 * nf + 1], acc[mf][nf], 0, 0, 0);
      }
#pragma unroll
    for (int mf = 0; mf < 4; ++mf)
#pragma unroll
      for (int nf = 0; nf < 2; ++nf) {
        acc[mf][2 + nf] = __builtin_amdgcn_mfma_f32_16x16x32_bf16(a[2 * mf], b1[2 * nf], acc[mf][2 + nf], 0, 0, 0);
        acc[mf][2 + nf] = __builtin_amdgcn_mfma_f32_16x16x32_bf16(a[2 * mf + 1], b1[2 * nf + 1], acc[mf][2 + nf], 0, 0, 0);
      }
    __builtin_amdgcn_s_setprio(0);

    // next-tile B half-2; a1 into a[] (a0's registers)
    if (u + 1 < NKT) loadBh(u + 1, 1, L2);
#pragma unroll
    for (int mf = 0; mf < 4; ++mf) {
      const int rb = ((mf + 4) * 16 + lr) << 7;
      a[2 * mf]     = *(const bf16x8*)(Ah + rb + c0);
      a[2 * mf + 1] = *(const bf16x8*)(Ah + rb + c1);
    }

    // convert+write B half-1 (Bs[nxt]; its last readers drained at tile u-1 end barrier)
    if (u + 1 < NKT) {
      asm volatile("s_waitcnt vmcnt(4)" ::: "memory");  // retire A(u+1)+Bh1, keep Bh2
      writeBh(u + 1, 0, L1);
    }

    // all reads of this tile's buffers drained chip-wide before stageA(u+2) overwrites As[cur]
    if (u + 2 < NKT) {
      asm volatile("s_waitcnt lgkmcnt(0)" ::: "memory");
      __builtin_amdgcn_s_barrier();
      stageA(0, u + 2); stageA(1, u + 2);
    }

    __builtin_amdgcn_s_setprio(1);
    // q(1,0), q(1,1): register-only (a1, b0, b1 held) — covers stage/convert shadow
#pragma unroll
    for (int mf = 0; mf < 4; ++mf)
#pragma unroll
      for (int nf = 0; nf < 2; ++nf) {
        acc[4 + mf][nf] = __builtin_amdgcn_mfma_f32_16x16x32_bf16(a[2 * mf], b0[2 * nf], acc[4 + mf][nf], 0, 0, 0);
        acc[4 + mf][nf] = __builtin_amdgcn_mfma_f32_16x16x32_bf16(a[2 * mf + 1], b0[2 * nf + 1], acc[4 + mf][nf], 0, 0, 0);
      }
#pragma unroll
    for (int mf = 0; mf < 4; ++mf)
#pragma unroll
      for (int nf = 0; nf < 2; ++nf) {
        acc[4 + mf][2 + nf] = __builtin_amdgcn_mfma_f32_16x16x32_bf16(a[2 * mf], b1[2 * nf], acc[4 + mf][2 + nf], 0, 0, 0);
        acc[4 + mf][2 + nf] = __builtin_amdgcn_mfma_f32_16x16x32_bf16(a[2 * mf + 1], b1[2 * nf + 1], acc[4 + mf][2 + nf], 0, 0, 0);
      }
    __builtin_amdgcn_s_setprio(0);

    // convert+write B half-2, then publish to next tile
    if (u + 1 < NKT) {
      if (u + 2 < NKT) {
        asm volatile("s_waitcnt vmcnt(4)" ::: "memory");  // retire Bh2, keep A(u+2)
      } else {
        asm volatile("s_waitcnt vmcnt(0)" ::: "memory");  // no A(u+2) in flight
      }
      writeBh(u + 1, 1, L2);
      asm volatile("s_waitcnt lgkmcnt(0)" ::: "memory");  // drain own ds_writes
      __builtin_amdgcn_s_barrier();
    }
  }

  // epilogue: D col = lane&15 (N), row = (lane>>4)*4 + reg (M)
  const int lg = (l >> 4) * 4;
#pragma unroll
  for (int mf = 0; mf < 8; ++mf)
#pragma unroll
    for (int nf = 0; nf < 4; ++nf)
#pragma unroll
      for (int r = 0; r < 4; ++r) {
        const int row = mt * 256 + wr * 128 + mf * 16 + lg + r;
        const int col = nt * 256 + wc * 64 + nf * 16 + lr;
        C[(size_t)row * VOC + col] = f2bf(acc[mf][nf][r]);
      }
}

// ---------------- per-token JSD ----------------
__device__ __forceinline__ void merge_ms(float& m, float& s, float om, float os) {
  float nm = fmaxf(m, om);
  s = s * __expf(m - nm) + os * __expf(om - nm);
  m = nm;
}

__global__ __launch_bounds__(256) void jsd_kernel(const unsigned short* __restrict__ SL,
                                                  const unsigned short* __restrict__ TL,
                                                  float* __restrict__ partials) {
  const int t = blockIdx.x;
  const int tid = threadIdx.x;
  const unsigned short* srow = SL + (size_t)t * VOC;
  const unsigned short* trow = TL + (size_t)t * VOC;

  float ms = -INFINITY, ss = 0.f, mt_ = -INFINITY, st = 0.f;
  for (int c = tid; c < VOC / 8; c += 256) {
    u16x8 vs = *(const u16x8*)(srow + c * 8);
    u16x8 vt = *(const u16x8*)(trow + c * 8);
    float zs[8], zt[8];
    float m8s = -INFINITY, m8t = -INFINITY;
#pragma unroll
    for (int j = 0; j < 8; ++j) {
      zs[j] = bf2f(vs[j]); zt[j] = bf2f(vt[j]);
      m8s = fmaxf(m8s, zs[j]); m8t = fmaxf(m8t, zt[j]);
    }
    float nms = fmaxf(ms, m8s);
    float es = 0.f;
#pragma unroll
    for (int j = 0; j < 8; ++j) es += __expf(zs[j] - nms);
    ss = ss * __expf(ms - nms) + es; ms = nms;
    float nmt = fmaxf(mt_, m8t);
    float et = 0.f;
#pragma unroll
    for (int j = 0; j < 8; ++j) et += __expf(zt[j] - nmt);
    st = st * __expf(mt_ - nmt) + et; mt_ = nmt;
  }
#pragma unroll
  for (int off = 32; off > 0; off >>= 1) {
    float om = __shfl_xor(ms, off), os = __shfl_xor(ss, off);
    merge_ms(ms, ss, om, os);
    float omt = __shfl_xor(mt_, off), ost = __shfl_xor(st, off);
    merge_ms(mt_, st, omt, ost);
  }
  __shared__ float red[4][4];
  const int w = tid >> 6;
  if ((tid & 63) == 0) { red[w][0] = ms; red[w][1] = ss; red[w][2] = mt_; red[w][3] = st; }
  __syncthreads();
  float Ms = red[0][0], Ss = red[0][1], Mt = red[0][2], St = red[0][3];
#pragma unroll
  for (int i = 1; i < 4; ++i) {
    merge_ms(Ms, Ss, red[i][0], red[i][1]);
    merge_ms(Mt, St, red[i][2], red[i][3]);
  }
  const float logZs = Ms + __logf(Ss);
  const float logZt = Mt + __logf(St);

  float acc = 0.f;
  for (int c = tid; c < VOC / 8; c += 256) {
    u16x8 vs = *(const u16x8*)(srow + c * 8);
    u16x8 vt = *(const u16x8*)(trow + c * 8);
#pragma unroll
    for (int j = 0; j < 8; ++j) {
      float lq = bf2f(vs[j]) - logZs;
      float lp = bf2f(vt[j]) - logZt;
      float mx = fmaxf(lp, lq), mn = fminf(lp, lq);
      float lm = mx + log1pf(__expf(mn - mx)) - 0.69314718f;
      acc += __expf(lp) * (lp - lm) + __expf(lq) * (lq - lm);
    }
  }
  acc *= 0.5f;
#pragma unroll
  for (int off = 32; off > 0; off >>= 1) acc += __shfl_xor(acc, off);
  __shared__ float red2[4];
  if ((tid & 63) == 0) red2[w] = acc;
  __syncthreads();
  if (tid == 0) partials[t] = red2[0] + red2[1] + red2[2] + red2[3];
}

__global__ __launch_bounds__(256) void final_reduce(const float* __restrict__ partials,
                                                    float* __restrict__ out) {
  float a = 0.f;
  for (int i = threadIdx.x; i < TOK; i += 256) a += partials[i];
#pragma unroll
  for (int off = 32; off > 0; off >>= 1) a += __shfl_xor(a, off);
  __shared__ float red[4];
  const int w = threadIdx.x >> 6;
  if ((threadIdx.x & 63) == 0) red[w] = a;
  __syncthreads();
  if (threadIdx.x == 0) out[0] = (red[0] + red[1] + red[2] + red[3]) * (1.0f / TOK);
}

// ---------------- launch ----------------
extern "C" void kernel_launch(void* const* d_in, const int* in_sizes, int n_in,
                              void* d_out, int out_size, void* d_ws, size_t ws_size,
                              hipStream_t stream) {
  const float* sIn = (const float*)d_in[0];
  const float* tIn = (const float*)d_in[1];
  const float* sW  = (const float*)d_in[2];
  const float* tW  = (const float*)d_in[3];
  float* out = (float*)d_out;

  unsigned short* ws = (unsigned short*)d_ws;
  unsigned short* sA  = ws;                        // 2048*4096 bf16
  unsigned short* tA  = sA  + (long)TOK * HID;     // 2048*4096
  unsigned short* sL  = tA  + (long)TOK * HID;     // 2048*32000
  unsigned short* tL  = sL  + (long)TOK * VOC;     // 2048*32000
  float* partials = (float*)(tL + (long)TOK * VOC);

  cast_f32_bf16<<<2048, 256, 0, stream>>>(sIn, sA, (long)TOK * HID);
  cast_f32_bf16<<<2048, 256, 0, stream>>>(tIn, tA, (long)TOK * HID);

  const int nblk = (TOK / 256) * (VOC / 256);  // 8 * 125 = 1000
  gemm256f<<<nblk, 512, 0, stream>>>(sA, sW, sL);
  gemm256f<<<nblk, 512, 0, stream>>>(tA, tW, tL);

  jsd_kernel<<<TOK, 256, 0, stream>>>(sL, tL, partials);
  final_reduce<<<1, 256, 0, stream>>>(partials, out);
}

// Round 6
// 1689.280 us; speedup vs baseline: 2.0432x; 1.1342x over previous
//
#include <hip/hip_runtime.h>
#include <stdint.h>

#define TOK 2048
#define HID 4096
#define VOC 32000
#define NKT (HID / 64)  // 64 K-tiles of BK=64

typedef __attribute__((ext_vector_type(4))) float f32x4;
typedef __attribute__((ext_vector_type(8))) short bf16x8;
typedef __attribute__((ext_vector_type(8))) unsigned short u16x8;

__device__ __forceinline__ float bf2f(unsigned short u) {
  return __uint_as_float(((unsigned int)u) << 16);
}
__device__ __forceinline__ unsigned short f2bf(float f) {
  unsigned int u = __float_as_uint(f);
  u += 0x7FFFu + ((u >> 16) & 1u);  // round-to-nearest-even
  return (unsigned short)(u >> 16);
}
// packed f32x2 -> bf16x2 (RNE), dst.lo = a, dst.hi = b
__device__ __forceinline__ unsigned int cvt2(float a, float b) {
  unsigned int r;
  asm volatile("v_cvt_pk_bf16_f32 %0, %1, %2" : "=v"(r) : "v"(a), "v"(b));
  return r;
}

// ---------------- cast f32 -> bf16 (inputs only; weights converted in-GEMM) ----------------
__global__ __launch_bounds__(256) void cast_f32_bf16(const float* __restrict__ in,
                                                     unsigned short* __restrict__ out,
                                                     long n) {
  long i = ((long)blockIdx.x * 256 + threadIdx.x) * 4;
  const long stride = (long)gridDim.x * 256 * 4;
  for (; i < n; i += stride) {
    const float4 v = *(const float4*)(in + i);
    ushort4 o;
    o.x = f2bf(v.x); o.y = f2bf(v.y); o.z = f2bf(v.z); o.w = f2bf(v.w);
    *(ushort4*)(out + i) = o;
  }
}

// ---------------- async global -> LDS (16B/lane) ----------------
__device__ __forceinline__ void gload_lds16(const void* g, void* l) {
  __builtin_amdgcn_global_load_lds(
      (const __attribute__((address_space(1))) unsigned int*)(uintptr_t)g,
      (__attribute__((address_space(3))) unsigned int*)(uintptr_t)l,
      16, 0, 0);
}

// ---------------- 256x256 bf16 GEMM with fused f32->bf16 B staging (deep pipeline) ----------------
// C[M,N] = A[M,K] * Bf[N,K]^T, A bf16 (pre-cast), Bf float32 (converted in-kernel).
// 8 waves (2M x 4N), BK=64, LDS 2dbuf x 2half x [128][64] for A and B (128 KiB).
// Persistent L regs always hold B(u+1) f32. Per tile u:
//   writeB(u+1) from L | loadB(u+2)->L | ds b0,b1,a0 | q00,q01 (a0 dies) | ds a1 |
//   lgkm0+bar | stageA(u+2) | q10,q11 (reg-only) | vmcnt(4)+bar.
// FIFO ledger (steady): entry {A(u+1):4}; +B32(u+2):8; +A(u+2):4 = 16; end vmcnt(4)
// retires A(u+1)+B32(u+2) (both ~full tile old), keeps A(u+2). ONE vmcnt/tile.
__global__ __launch_bounds__(512, 2) void gemm256f(const unsigned short* __restrict__ A,
                                                   const float* __restrict__ Bf,
                                                   unsigned short* __restrict__ C) {
  __shared__ unsigned short As[2][2][128 * 64];
  __shared__ unsigned short Bs[2][2][128 * 64];
  const int tid = threadIdx.x;
  const int w = tid >> 6;
  const int l = tid & 63;
  const int wr = w >> 2;   // 0..1 (M half)
  const int wc = w & 3;    // 0..3 (N quarter)

  // T1: XCD-aware swizzle. grid = 1000 blocks, 1000 % 8 == 0.
  const int bid = blockIdx.x;
  const int cpx = gridDim.x >> 3;                 // 125
  const int swz = (bid & 7) * cpx + (bid >> 3);
  const int mt = swz & 7;                         // 8 M-tiles
  const int nt = swz >> 3;                        // 125 N-tiles

  const size_t Abase = (size_t)mt * 256 * HID;

  f32x4 acc[8][4] = {};

  // ---- A staging (gload_lds, pre-swizzled source) ----
  const int r8 = l >> 3;
  const int scol = ((l & 7) ^ r8) << 3;  // swizzled source column (elements)
  auto stageA = [&](int half, int v) {
    const unsigned short* src = A + Abase + (size_t)half * 128 * HID + (size_t)v * 64 + scol;
#pragma unroll
    for (int i = 0; i < 2; ++i) {
      const int c = 2 * w + i;
      gload_lds16(src + (size_t)(c * 8 + r8) * HID, &As[v & 1][half][c * 512]);
    }
  };

  // ---- B staging (f32 global -> persistent regs -> cvt -> swizzled ds_write) ----
  // thread t: logical B-tile row rB = t>>1 (0..255), cols (t&1)*32 .. +31 (f32)
  const int rB = tid >> 1;
  const int rhalf = rB >> 7;
  const int rrow = rB & 127;
  const int swzB = (rB & 7) << 4;
  const int tcol = (tid & 1) << 6;  // byte col base — XORed with swzB
  const float* bsrc = Bf + (size_t)(nt * 256 + rB) * HID + (tid & 1) * 32;

  auto loadB = [&](int v, float4* Lb) {
#pragma unroll
    for (int j = 0; j < 8; ++j)
      Lb[j] = *(const float4*)(bsrc + (size_t)v * 64 + j * 4);
  };
  auto writeB = [&](int v, const float4* Lb) {
    char* dst = (char*)&Bs[v & 1][rhalf][0] + (rrow << 7);
#pragma unroll
    for (int g = 0; g < 4; ++g) {
      uint4 wv;
      wv.x = cvt2(Lb[2 * g].x, Lb[2 * g].y);
      wv.y = cvt2(Lb[2 * g].z, Lb[2 * g].w);
      wv.z = cvt2(Lb[2 * g + 1].x, Lb[2 * g + 1].y);
      wv.w = cvt2(Lb[2 * g + 1].z, Lb[2 * g + 1].w);
      *(uint4*)(dst + ((tcol | (16 * g)) ^ swzB)) = wv;
    }
  };

  float4 L[8];  // persistent: holds B(u+1) f32 across tile u

  // ---- prologue ----
  {
    float4 P[8];
    loadB(0, P);                        // B32(0):8
    stageA(0, 0); stageA(1, 0);         // +A(0):4 = 12
    stageA(0, 1); stageA(1, 1);         // +A(1):4 = 16
    asm volatile("s_waitcnt vmcnt(8)" ::: "memory");   // retire B32(0)
    writeB(0, P);
    loadB(1, L);                        // +B32(1):8 -> {A(0):4, A(1):4, B32(1):8}
    asm volatile("s_waitcnt vmcnt(12)" ::: "memory");  // retire A(0); keep A(1),B32(1)
    asm volatile("s_waitcnt lgkmcnt(0)" ::: "memory"); // drain writeB(0)
    __builtin_amdgcn_s_barrier();
  }

  const int lr = l & 15;
  const int c0 = ((l >> 4) << 4) ^ ((lr & 7) << 4);  // byte col for kk=0
  const int c1 = c0 ^ 64;                            // byte col for kk=32
  const int brow = (wc & 1) * 64;                    // wave's N-row base in its B half

#pragma unroll 2
  for (int u = 0; u < NKT; ++u) {
    const int cur = u & 1;
    const char* Ah = (const char*)&As[cur][wr][0];
    const char* Bh = (const char*)&Bs[cur][wc >> 1][0];
    bf16x8 a[8], b0[4], b1[4];

    // publish B(u+1) from L (readers of Bs[nxt] drained at u-1 mid barrier;
    // B32(u+1) loads retired by u-1 end vmcnt(4))
    if (u + 1 < NKT) writeB(u + 1, L);
    // fetch B(u+2) — waited only at NEXT tile's entry (full-tile cover)
    if (u + 2 < NKT) loadB(u + 2, L);

    // ds_reads: b0, b1, a0
#pragma unroll
    for (int nf = 0; nf < 2; ++nf) {
      const int rb = (brow + nf * 16 + lr) << 7;
      b0[2 * nf]     = *(const bf16x8*)(Bh + rb + c0);
      b0[2 * nf + 1] = *(const bf16x8*)(Bh + rb + c1);
    }
#pragma unroll
    for (int nf = 0; nf < 2; ++nf) {
      const int rb = (brow + (nf + 2) * 16 + lr) << 7;
      b1[2 * nf]     = *(const bf16x8*)(Bh + rb + c0);
      b1[2 * nf + 1] = *(const bf16x8*)(Bh + rb + c1);
    }
#pragma unroll
    for (int mf = 0; mf < 4; ++mf) {
      const int rb = (mf * 16 + lr) << 7;
      a[2 * mf]     = *(const bf16x8*)(Ah + rb + c0);
      a[2 * mf + 1] = *(const bf16x8*)(Ah + rb + c1);
    }

    __builtin_amdgcn_s_setprio(1);
    // q(0,0): a0 x b0 ; q(0,1): a0 x b1  -> a0 dies
#pragma unroll
    for (int mf = 0; mf < 4; ++mf)
#pragma unroll
      for (int nf = 0; nf < 2; ++nf) {
        acc[mf][nf] = __builtin_amdgcn_mfma_f32_16x16x32_bf16(a[2 * mf], b0[2 * nf], acc[mf][nf], 0, 0, 0);
        acc[mf][nf] = __builtin_amdgcn_mfma_f32_16x16x32_bf16(a[2 * mf + 1], b0[2 * nf + 1], acc[mf][nf], 0, 0, 0);
      }
#pragma unroll
    for (int mf = 0; mf < 4; ++mf)
#pragma unroll
      for (int nf = 0; nf < 2; ++nf) {
        acc[mf][2 + nf] = __builtin_amdgcn_mfma_f32_16x16x32_bf16(a[2 * mf], b1[2 * nf], acc[mf][2 + nf], 0, 0, 0);
        acc[mf][2 + nf] = __builtin_amdgcn_mfma_f32_16x16x32_bf16(a[2 * mf + 1], b1[2 * nf + 1], acc[mf][2 + nf], 0, 0, 0);
      }
    __builtin_amdgcn_s_setprio(0);

    // a1 into a[] (a0's registers)
#pragma unroll
    for (int mf = 0; mf < 4; ++mf) {
      const int rb = ((mf + 4) * 16 + lr) << 7;
      a[2 * mf]     = *(const bf16x8*)(Ah + rb + c0);
      a[2 * mf + 1] = *(const bf16x8*)(Ah + rb + c1);
    }

    // mid: all reads of As[cur]/Bs[cur] + my writeB drained before stageA(u+2)
    asm volatile("s_waitcnt lgkmcnt(0)" ::: "memory");
    __builtin_amdgcn_s_barrier();
    if (u + 2 < NKT) { stageA(0, u + 2); stageA(1, u + 2); }

    __builtin_amdgcn_s_setprio(1);
    // q(1,0), q(1,1): register-only (a1, b0, b1 held) — covers stage shadow
#pragma unroll
    for (int mf = 0; mf < 4; ++mf)
#pragma unroll
      for (int nf = 0; nf < 2; ++nf) {
        acc[4 + mf][nf] = __builtin_amdgcn_mfma_f32_16x16x32_bf16(a[2 * mf], b0[2 * nf], acc[4 + mf][nf], 0, 0, 0);
        acc[4 + mf][nf] = __builtin_amdgcn_mfma_f32_16x16x32_bf16(a[2 * mf + 1], b0[2 * nf + 1], acc[4 + mf][nf], 0, 0, 0);
      }
#pragma unroll
    for (int mf = 0; mf < 4; ++mf)
#pragma unroll
      for (int nf = 0; nf < 2; ++nf) {
        acc[4 + mf][2 + nf] = __builtin_amdgcn_mfma_f32_16x16x32_bf16(a[2 * mf], b1[2 * nf], acc[4 + mf][2 + nf], 0, 0, 0);
        acc[4 + mf][2 + nf] = __builtin_amdgcn_mfma_f32_16x16x32_bf16(a[2 * mf + 1], b1[2 * nf + 1], acc[4 + mf][2 + nf], 0, 0, 0);
      }
    __builtin_amdgcn_s_setprio(0);

    // end: single counted vmcnt (full-tile-old loads), publish to next tile
    if (u + 1 < NKT) {
      if (u + 2 < NKT) {
        asm volatile("s_waitcnt vmcnt(4)" ::: "memory");  // retire A(u+1)+B32(u+2), keep A(u+2)
      } else {
        asm volatile("s_waitcnt vmcnt(0)" ::: "memory");  // u=62: retire A(63)
      }
      __builtin_amdgcn_s_barrier();
    }
  }

  // epilogue: D col = lane&15 (N), row = (lane>>4)*4 + reg (M)
  const int lg = (l >> 4) * 4;
#pragma unroll
  for (int mf = 0; mf < 8; ++mf)
#pragma unroll
    for (int nf = 0; nf < 4; ++nf)
#pragma unroll
      for (int r = 0; r < 4; ++r) {
        const int row = mt * 256 + wr * 128 + mf * 16 + lg + r;
        const int col = nt * 256 + wc * 64 + nf * 16 + lr;
        C[(size_t)row * VOC + col] = f2bf(acc[mf][nf][r]);
      }
}

// ---------------- per-token JSD ----------------
__device__ __forceinline__ void merge_ms(float& m, float& s, float om, float os) {
  float nm = fmaxf(m, om);
  s = s * __expf(m - nm) + os * __expf(om - nm);
  m = nm;
}

__global__ __launch_bounds__(256) void jsd_kernel(const unsigned short* __restrict__ SL,
                                                  const unsigned short* __restrict__ TL,
                                                  float* __restrict__ partials) {
  const int t = blockIdx.x;
  const int tid = threadIdx.x;
  const unsigned short* srow = SL + (size_t)t * VOC;
  const unsigned short* trow = TL + (size_t)t * VOC;

  float ms = -INFINITY, ss = 0.f, mt_ = -INFINITY, st = 0.f;
  for (int c = tid; c < VOC / 8; c += 256) {
    u16x8 vs = *(const u16x8*)(srow + c * 8);
    u16x8 vt = *(const u16x8*)(trow + c * 8);
    float zs[8], zt[8];
    float m8s = -INFINITY, m8t = -INFINITY;
#pragma unroll
    for (int j = 0; j < 8; ++j) {
      zs[j] = bf2f(vs[j]); zt[j] = bf2f(vt[j]);
      m8s = fmaxf(m8s, zs[j]); m8t = fmaxf(m8t, zt[j]);
    }
    float nms = fmaxf(ms, m8s);
    float es = 0.f;
#pragma unroll
    for (int j = 0; j < 8; ++j) es += __expf(zs[j] - nms);
    ss = ss * __expf(ms - nms) + es; ms = nms;
    float nmt = fmaxf(mt_, m8t);
    float et = 0.f;
#pragma unroll
    for (int j = 0; j < 8; ++j) et += __expf(zt[j] - nmt);
    st = st * __expf(mt_ - nmt) + et; mt_ = nmt;
  }
#pragma unroll
  for (int off = 32; off > 0; off >>= 1) {
    float om = __shfl_xor(ms, off), os = __shfl_xor(ss, off);
    merge_ms(ms, ss, om, os);
    float omt = __shfl_xor(mt_, off), ost = __shfl_xor(st, off);
    merge_ms(mt_, st, omt, ost);
  }
  __shared__ float red[4][4];
  const int w = tid >> 6;
  if ((tid & 63) == 0) { red[w][0] = ms; red[w][1] = ss; red[w][2] = mt_; red[w][3] = st; }
  __syncthreads();
  float Ms = red[0][0], Ss = red[0][1], Mt = red[0][2], St = red[0][3];
#pragma unroll
  for (int i = 1; i < 4; ++i) {
    merge_ms(Ms, Ss, red[i][0], red[i][1]);
    merge_ms(Mt, St, red[i][2], red[i][3]);
  }
  const float logZs = Ms + __logf(Ss);
  const float logZt = Mt + __logf(St);

  float acc = 0.f;
  for (int c = tid; c < VOC / 8; c += 256) {
    u16x8 vs = *(const u16x8*)(srow + c * 8);
    u16x8 vt = *(const u16x8*)(trow + c * 8);
#pragma unroll
    for (int j = 0; j < 8; ++j) {
      float lq = bf2f(vs[j]) - logZs;
      float lp = bf2f(vt[j]) - logZt;
      float mx = fmaxf(lp, lq), mn = fminf(lp, lq);
      float lm = mx + log1pf(__expf(mn - mx)) - 0.69314718f;
      acc += __expf(lp) * (lp - lm) + __expf(lq) * (lq - lm);
    }
  }
  acc *= 0.5f;
#pragma unroll
  for (int off = 32; off > 0; off >>= 1) acc += __shfl_xor(acc, off);
  __shared__ float red2[4];
  if ((tid & 63) == 0) red2[w] = acc;
  __syncthreads();
  if (tid == 0) partials[t] = red2[0] + red2[1] + red2[2] + red2[3];
}

__global__ __launch_bounds__(256) void final_reduce(const float* __restrict__ partials,
                                                    float* __restrict__ out) {
  float a = 0.f;
  for (int i = threadIdx.x; i < TOK; i += 256) a += partials[i];
#pragma unroll
  for (int off = 32; off > 0; off >>= 1) a += __shfl_xor(a, off);
  __shared__ float red[4];
  const int w = threadIdx.x >> 6;
  if ((threadIdx.x & 63) == 0) red[w] = a;
  __syncthreads();
  if (threadIdx.x == 0) out[0] = (red[0] + red[1] + red[2] + red[3]) * (1.0f / TOK);
}

// ---------------- launch ----------------
extern "C" void kernel_launch(void* const* d_in, const int* in_sizes, int n_in,
                              void* d_out, int out_size, void* d_ws, size_t ws_size,
                              hipStream_t stream) {
  const float* sIn = (const float*)d_in[0];
  const float* tIn = (const float*)d_in[1];
  const float* sW  = (const float*)d_in[2];
  const float* tW  = (const float*)d_in[3];
  float* out = (float*)d_out;

  unsigned short* ws = (unsigned short*)d_ws;
  unsigned short* sA  = ws;                        // 2048*4096 bf16
  unsigned short* tA  = sA  + (long)TOK * HID;     // 2048*4096
  unsigned short* sL  = tA  + (long)TOK * HID;     // 2048*32000
  unsigned short* tL  = sL  + (long)TOK * VOC;     // 2048*32000
  float* partials = (float*)(tL + (long)TOK * VOC);

  cast_f32_bf16<<<2048, 256, 0, stream>>>(sIn, sA, (long)TOK * HID);
  cast_f32_bf16<<<2048, 256, 0, stream>>>(tIn, tA, (long)TOK * HID);

  const int nblk = (TOK / 256) * (VOC / 256);  // 8 * 125 = 1000
  gemm256f<<<nblk, 512, 0, stream>>>(sA, sW, sL);
  gemm256f<<<nblk, 512, 0, stream>>>(tA, tW, tL);

  jsd_kernel<<<TOK, 256, 0, stream>>>(sL, tL, partials);
  final_reduce<<<1, 256, 0, stream>>>(partials, out);
}

// Round 7
// 1419.267 us; speedup vs baseline: 2.4319x; 1.1902x over previous
//
#include <hip/hip_runtime.h>
#include <stdint.h>

#define TOK 2048
#define HID 4096
#define VOC 32000
#define NKT (HID / 64)  // 64 K-tiles of BK=64

typedef __attribute__((ext_vector_type(4))) float f32x4;
typedef __attribute__((ext_vector_type(8))) short bf16x8;
typedef __attribute__((ext_vector_type(8))) unsigned short u16x8;

__device__ __forceinline__ float bf2f(unsigned short u) {
  return __uint_as_float(((unsigned int)u) << 16);
}
__device__ __forceinline__ unsigned short f2bf(float f) {
  unsigned int u = __float_as_uint(f);
  u += 0x7FFFu + ((u >> 16) & 1u);  // round-to-nearest-even
  return (unsigned short)(u >> 16);
}

// ---------------- cast f32 -> bf16 ----------------
__global__ __launch_bounds__(256) void cast_f32_bf16(const float* __restrict__ in,
                                                     unsigned short* __restrict__ out,
                                                     long n) {
  long i = ((long)blockIdx.x * 256 + threadIdx.x) * 4;
  const long stride = (long)gridDim.x * 256 * 4;
  for (; i < n; i += stride) {
    const float4 v = *(const float4*)(in + i);
    ushort4 o;
    o.x = f2bf(v.x); o.y = f2bf(v.y); o.z = f2bf(v.z); o.w = f2bf(v.w);
    *(ushort4*)(out + i) = o;
  }
}

// ---------------- async global -> LDS (16B/lane) ----------------
__device__ __forceinline__ void gload_lds16(const void* g, void* l) {
  __builtin_amdgcn_global_load_lds(
      (const __attribute__((address_space(1))) unsigned int*)(uintptr_t)g,
      (__attribute__((address_space(3))) unsigned int*)(uintptr_t)l,
      16, 0, 0);
}

// ---------------- 256x256 bf16 GEMM, ONE-barrier-per-K-tile ----------------
// C[M,N] = A[M,K] * B[N,K]^T, both bf16 (weights pre-cast).
// 8 waves (2M x 4N), BK=64, LDS 2dbuf x 2half x [128][64] for A and B (128 KiB).
// Swizzle: byte ^= ((row&7)<<4) (pre-swizzled global source, same XOR on ds_read).
// Hazard analysis (round-6 simplification): both A and B stage 1-AHEAD into buf
// nxt, whose last readers (tile u-1) finished their ds_reads before their MFMAs,
// which finished before tile u-1's end barrier -> staging at tile u is safe with
// NO mid-tile lgkm drain/barrier. End-of-tile vmcnt(0) waits on stages issued a
// full tile (~2900 cyc) earlier >> HBM latency -> near-free.
__global__ __launch_bounds__(512, 2) void gemm256(const unsigned short* __restrict__ A,
                                                  const unsigned short* __restrict__ B,
                                                  unsigned short* __restrict__ C) {
  __shared__ unsigned short As[2][2][128 * 64];
  __shared__ unsigned short Bs[2][2][128 * 64];
  const int tid = threadIdx.x;
  const int w = tid >> 6;
  const int l = tid & 63;
  const int wr = w >> 2;   // 0..1 (M half)
  const int wc = w & 3;    // 0..3 (N quarter)

  // T1: XCD-aware swizzle. grid = 1000 blocks, 1000 % 8 == 0.
  const int bid = blockIdx.x;
  const int cpx = gridDim.x >> 3;                 // 125
  const int swz = (bid & 7) * cpx + (bid >> 3);
  const int mt = swz & 7;                         // 8 M-tiles
  const int nt = swz >> 3;                        // 125 N-tiles

  const size_t Abase = (size_t)mt * 256 * HID;
  const size_t Bbase = (size_t)nt * 256 * HID;

  f32x4 acc[8][4] = {};

  // staging: chunk c (1 KiB) = rows c*8..c*8+7 of a [128][64] half.
  // linear LDS dest byte d = c*1024 + l*16; logical = d ^ ((row&7)<<4), row&7 = l>>3.
  const int r8 = l >> 3;
  const int scol = ((l & 7) ^ r8) << 3;  // swizzled source column (elements)

  auto stageA = [&](int half, int v) {
    const unsigned short* src = A + Abase + (size_t)half * 128 * HID + (size_t)v * 64 + scol;
#pragma unroll
    for (int i = 0; i < 2; ++i) {
      const int c = 2 * w + i;
      gload_lds16(src + (size_t)(c * 8 + r8) * HID, &As[v & 1][half][c * 512]);
    }
  };
  auto stageB = [&](int half, int v) {
    const unsigned short* src = B + Bbase + (size_t)half * 128 * HID + (size_t)v * 64 + scol;
#pragma unroll
    for (int i = 0; i < 2; ++i) {
      const int c = 2 * w + i;
      gload_lds16(src + (size_t)(c * 8 + r8) * HID, &Bs[v & 1][half][c * 512]);
    }
  };

  // prologue: tile 0 only (1-deep pipeline)
  stageA(0, 0); stageA(1, 0); stageB(0, 0); stageB(1, 0);
  asm volatile("s_waitcnt vmcnt(0)" ::: "memory");
  __builtin_amdgcn_s_barrier();

  const int lr = l & 15;
  const int c0 = ((l >> 4) << 4) ^ ((lr & 7) << 4);  // byte col for kk=0
  const int c1 = c0 ^ 64;                            // byte col for kk=32
  const int brow = (wc & 1) * 64;                    // wave's N-row base in its B half

#pragma unroll 2
  for (int u = 0; u < NKT; ++u) {
    const int cur = u & 1;
    const char* Ah = (const char*)&As[cur][wr][0];
    const char* Bh = (const char*)&Bs[cur][wc >> 1][0];
    bf16x8 a0[8], a1[8], b0[4], b1[4];

    // ---- issue all 24 ds_reads (compiler schedules + counted auto-lgkmcnt) ----
#pragma unroll
    for (int mf = 0; mf < 4; ++mf) {
      const int rb = (mf * 16 + lr) << 7;
      a0[2 * mf]     = *(const bf16x8*)(Ah + rb + c0);
      a0[2 * mf + 1] = *(const bf16x8*)(Ah + rb + c1);
    }
#pragma unroll
    for (int nf = 0; nf < 2; ++nf) {
      const int rb = (brow + nf * 16 + lr) << 7;
      b0[2 * nf]     = *(const bf16x8*)(Bh + rb + c0);
      b0[2 * nf + 1] = *(const bf16x8*)(Bh + rb + c1);
    }
#pragma unroll
    for (int mf = 0; mf < 4; ++mf) {
      const int rb = ((mf + 4) * 16 + lr) << 7;
      a1[2 * mf]     = *(const bf16x8*)(Ah + rb + c0);
      a1[2 * mf + 1] = *(const bf16x8*)(Ah + rb + c1);
    }
#pragma unroll
    for (int nf = 0; nf < 2; ++nf) {
      const int rb = (brow + (nf + 2) * 16 + lr) << 7;
      b1[2 * nf]     = *(const bf16x8*)(Bh + rb + c0);
      b1[2 * nf + 1] = *(const bf16x8*)(Bh + rb + c1);
    }

    // stage tile u+1 (both operands) into buf nxt — safe: nxt's last readers
    // drained before tile u-1's end barrier
    if (u + 1 < NKT) {
      stageB(0, u + 1); stageB(1, u + 1);
      stageA(0, u + 1); stageA(1, u + 1);
    }

    __builtin_amdgcn_s_setprio(1);
    // all 4 quadrants, 64 MFMA (compiler interleaves with auto lgkm waits)
#pragma unroll
    for (int mf = 0; mf < 4; ++mf)
#pragma unroll
      for (int nf = 0; nf < 2; ++nf) {
        acc[mf][nf] = __builtin_amdgcn_mfma_f32_16x16x32_bf16(a0[2 * mf], b0[2 * nf], acc[mf][nf], 0, 0, 0);
        acc[mf][nf] = __builtin_amdgcn_mfma_f32_16x16x32_bf16(a0[2 * mf + 1], b0[2 * nf + 1], acc[mf][nf], 0, 0, 0);
      }
#pragma unroll
    for (int mf = 0; mf < 4; ++mf)
#pragma unroll
      for (int nf = 0; nf < 2; ++nf) {
        acc[4 + mf][nf] = __builtin_amdgcn_mfma_f32_16x16x32_bf16(a1[2 * mf], b0[2 * nf], acc[4 + mf][nf], 0, 0, 0);
        acc[4 + mf][nf] = __builtin_amdgcn_mfma_f32_16x16x32_bf16(a1[2 * mf + 1], b0[2 * nf + 1], acc[4 + mf][nf], 0, 0, 0);
      }
#pragma unroll
    for (int mf = 0; mf < 4; ++mf)
#pragma unroll
      for (int nf = 0; nf < 2; ++nf) {
        acc[4 + mf][2 + nf] = __builtin_amdgcn_mfma_f32_16x16x32_bf16(a1[2 * mf], b1[2 * nf], acc[4 + mf][2 + nf], 0, 0, 0);
        acc[4 + mf][2 + nf] = __builtin_amdgcn_mfma_f32_16x16x32_bf16(a1[2 * mf + 1], b1[2 * nf + 1], acc[4 + mf][2 + nf], 0, 0, 0);
      }
#pragma unroll
    for (int mf = 0; mf < 4; ++mf)
#pragma unroll
      for (int nf = 0; nf < 2; ++nf) {
        acc[mf][2 + nf] = __builtin_amdgcn_mfma_f32_16x16x32_bf16(a0[2 * mf], b1[2 * nf], acc[mf][2 + nf], 0, 0, 0);
        acc[mf][2 + nf] = __builtin_amdgcn_mfma_f32_16x16x32_bf16(a0[2 * mf + 1], b1[2 * nf + 1], acc[mf][2 + nf], 0, 0, 0);
      }
    __builtin_amdgcn_s_setprio(0);

    // single sync point: next tile's stages (issued ~full tile ago) must land
    if (u + 1 < NKT) {
      asm volatile("s_waitcnt vmcnt(0)" ::: "memory");
      __builtin_amdgcn_s_barrier();
    }
  }

  // epilogue: D col = lane&15 (N), row = (lane>>4)*4 + reg (M)
  const int lg = (l >> 4) * 4;
#pragma unroll
  for (int mf = 0; mf < 8; ++mf)
#pragma unroll
    for (int nf = 0; nf < 4; ++nf)
#pragma unroll
      for (int r = 0; r < 4; ++r) {
        const int row = mt * 256 + wr * 128 + mf * 16 + lg + r;
        const int col = nt * 256 + wc * 64 + nf * 16 + lr;
        C[(size_t)row * VOC + col] = f2bf(acc[mf][nf][r]);
      }
}

// ---------------- per-token JSD ----------------
__device__ __forceinline__ void merge_ms(float& m, float& s, float om, float os) {
  float nm = fmaxf(m, om);
  s = s * __expf(m - nm) + os * __expf(om - nm);
  m = nm;
}

__global__ __launch_bounds__(256) void jsd_kernel(const unsigned short* __restrict__ SL,
                                                  const unsigned short* __restrict__ TL,
                                                  float* __restrict__ partials) {
  const int t = blockIdx.x;
  const int tid = threadIdx.x;
  const unsigned short* srow = SL + (size_t)t * VOC;
  const unsigned short* trow = TL + (size_t)t * VOC;

  float ms = -INFINITY, ss = 0.f, mt_ = -INFINITY, st = 0.f;
  for (int c = tid; c < VOC / 8; c += 256) {
    u16x8 vs = *(const u16x8*)(srow + c * 8);
    u16x8 vt = *(const u16x8*)(trow + c * 8);
    float zs[8], zt[8];
    float m8s = -INFINITY, m8t = -INFINITY;
#pragma unroll
    for (int j = 0; j < 8; ++j) {
      zs[j] = bf2f(vs[j]); zt[j] = bf2f(vt[j]);
      m8s = fmaxf(m8s, zs[j]); m8t = fmaxf(m8t, zt[j]);
    }
    float nms = fmaxf(ms, m8s);
    float es = 0.f;
#pragma unroll
    for (int j = 0; j < 8; ++j) es += __expf(zs[j] - nms);
    ss = ss * __expf(ms - nms) + es; ms = nms;
    float nmt = fmaxf(mt_, m8t);
    float et = 0.f;
#pragma unroll
    for (int j = 0; j < 8; ++j) et += __expf(zt[j] - nmt);
    st = st * __expf(mt_ - nmt) + et; mt_ = nmt;
  }
#pragma unroll
  for (int off = 32; off > 0; off >>= 1) {
    float om = __shfl_xor(ms, off), os = __shfl_xor(ss, off);
    merge_ms(ms, ss, om, os);
    float omt = __shfl_xor(mt_, off), ost = __shfl_xor(st, off);
    merge_ms(mt_, st, omt, ost);
  }
  __shared__ float red[4][4];
  const int w = tid >> 6;
  if ((tid & 63) == 0) { red[w][0] = ms; red[w][1] = ss; red[w][2] = mt_; red[w][3] = st; }
  __syncthreads();
  float Ms = red[0][0], Ss = red[0][1], Mt = red[0][2], St = red[0][3];
#pragma unroll
  for (int i = 1; i < 4; ++i) {
    merge_ms(Ms, Ss, red[i][0], red[i][1]);
    merge_ms(Mt, St, red[i][2], red[i][3]);
  }
  const float logZs = Ms + __logf(Ss);
  const float logZt = Mt + __logf(St);

  float acc = 0.f;
  for (int c = tid; c < VOC / 8; c += 256) {
    u16x8 vs = *(const u16x8*)(srow + c * 8);
    u16x8 vt = *(const u16x8*)(trow + c * 8);
#pragma unroll
    for (int j = 0; j < 8; ++j) {
      float lq = bf2f(vs[j]) - logZs;
      float lp = bf2f(vt[j]) - logZt;
      float mx = fmaxf(lp, lq), mn = fminf(lp, lq);
      float lm = mx + log1pf(__expf(mn - mx)) - 0.69314718f;
      acc += __expf(lp) * (lp - lm) + __expf(lq) * (lq - lm);
    }
  }
  acc *= 0.5f;
#pragma unroll
  for (int off = 32; off > 0; off >>= 1) acc += __shfl_xor(acc, off);
  __shared__ float red2[4];
  if ((tid & 63) == 0) red2[w] = acc;
  __syncthreads();
  if (tid == 0) partials[t] = red2[0] + red2[1] + red2[2] + red2[3];
}

__global__ __launch_bounds__(256) void final_reduce(const float* __restrict__ partials,
                                                    float* __restrict__ out) {
  float a = 0.f;
  for (int i = threadIdx.x; i < TOK; i += 256) a += partials[i];
#pragma unroll
  for (int off = 32; off > 0; off >>= 1) a += __shfl_xor(a, off);
  __shared__ float red[4];
  const int w = threadIdx.x >> 6;
  if ((threadIdx.x & 63) == 0) red[w] = a;
  __syncthreads();
  if (threadIdx.x == 0) out[0] = (red[0] + red[1] + red[2] + red[3]) * (1.0f / TOK);
}

// ---------------- launch ----------------
extern "C" void kernel_launch(void* const* d_in, const int* in_sizes, int n_in,
                              void* d_out, int out_size, void* d_ws, size_t ws_size,
                              hipStream_t stream) {
  const float* sIn = (const float*)d_in[0];
  const float* tIn = (const float*)d_in[1];
  const float* sW  = (const float*)d_in[2];
  const float* tW  = (const float*)d_in[3];
  float* out = (float*)d_out;

  unsigned short* ws = (unsigned short*)d_ws;
  unsigned short* sA  = ws;                        // 2048*4096 bf16
  unsigned short* tA  = sA  + (long)TOK * HID;     // 2048*4096
  unsigned short* sWb = tA  + (long)TOK * HID;     // 32000*4096
  unsigned short* tWb = sWb + (long)VOC * HID;     // 32000*4096
  unsigned short* sL  = tWb + (long)VOC * HID;     // 2048*32000
  unsigned short* tL  = sL  + (long)TOK * VOC;     // 2048*32000
  float* partials = (float*)(tL + (long)TOK * VOC);

  cast_f32_bf16<<<2048, 256, 0, stream>>>(sIn, sA, (long)TOK * HID);
  cast_f32_bf16<<<2048, 256, 0, stream>>>(tIn, tA, (long)TOK * HID);
  cast_f32_bf16<<<2048, 256, 0, stream>>>(sW, sWb, (long)VOC * HID);
  cast_f32_bf16<<<2048, 256, 0, stream>>>(tW, tWb, (long)VOC * HID);

  const int nblk = (TOK / 256) * (VOC / 256);  // 8 * 125 = 1000
  gemm256<<<nblk, 512, 0, stream>>>(sA, sWb, sL);
  gemm256<<<nblk, 512, 0, stream>>>(tA, tWb, tL);

  jsd_kernel<<<TOK, 256, 0, stream>>>(sL, tL, partials);
  final_reduce<<<1, 256, 0, stream>>>(partials, out);
}

// Round 9
// 1334.173 us; speedup vs baseline: 2.5870x; 1.0638x over previous
//
#include <hip/hip_runtime.h>
#include <stdint.h>

#define TOK 2048
#define HID 4096
#define VOC 32000
#define NKT (HID / 64)  // 64 K-tiles of BK=64
#define NNT (VOC / 256) // 125 N-tiles

typedef __attribute__((ext_vector_type(4))) float f32x4;
typedef __attribute__((ext_vector_type(8))) short bf16x8;
typedef __attribute__((ext_vector_type(8))) unsigned short u16x8;

__device__ __forceinline__ float bf2f(unsigned short u) {
  return __uint_as_float(((unsigned int)u) << 16);
}
__device__ __forceinline__ unsigned short f2bf(float f) {
  unsigned int u = __float_as_uint(f);
  u += 0x7FFFu + ((u >> 16) & 1u);  // round-to-nearest-even
  return (unsigned short)(u >> 16);
}

// ---------------- cast f32 -> bf16 ----------------
__global__ __launch_bounds__(256) void cast_f32_bf16(const float* __restrict__ in,
                                                     unsigned short* __restrict__ out,
                                                     long n) {
  long i = ((long)blockIdx.x * 256 + threadIdx.x) * 4;
  const long stride = (long)gridDim.x * 256 * 4;
  for (; i < n; i += stride) {
    const float4 v = *(const float4*)(in + i);
    ushort4 o;
    o.x = f2bf(v.x); o.y = f2bf(v.y); o.z = f2bf(v.z); o.w = f2bf(v.w);
    *(ushort4*)(out + i) = o;
  }
}

// ---------------- async global -> LDS (16B/lane) ----------------
__device__ __forceinline__ void gload_lds16(const void* g, void* l) {
  __builtin_amdgcn_global_load_lds(
      (const __attribute__((address_space(1))) unsigned int*)(uintptr_t)g,
      (__attribute__((address_space(3))) unsigned int*)(uintptr_t)l,
      16, 0, 0);
}

// NOTE: callers must NEVER pass -INFINITY for both m and om of the same lane:
// -inf - -inf = NaN. Empty slots use the finite sentinel -1e30f (exp underflows
// to exactly 0, so empty merges are identity).
__device__ __forceinline__ void merge_ms(float& m, float& s, float om, float os) {
  float nm = fmaxf(m, om);
  s = s * __expf(m - nm) + os * __expf(om - nm);
  m = nm;
}

// ---------------- 256x256 bf16 GEMM, both-2-ahead, counted vmcnt(8) ----------------
// C[M,N] = A[M,K] * B[N,K]^T, both bf16 (weights pre-cast). Fused row-LSE epilogue.
// 8 waves (2M x 4N), BK=64, LDS 2dbuf x 2half x [128][64] for A and B (128 KiB).
// Swizzle: byte ^= ((row&7)<<4) (pre-swizzled global source, same XOR on ds_read).
// Per tile u: 24 ds_reads | q00,q10,q11 | lgkm0+bar | stage A,B(u+2) into buf cur |
// q01 (reg-only) | vmcnt(8) retires stages(u+1) [issued 1.5 tiles ago], keeps (u+2) | bar.
__global__ __launch_bounds__(512, 2) void gemm256(const unsigned short* __restrict__ A,
                                                  const unsigned short* __restrict__ B,
                                                  unsigned short* __restrict__ C,
                                                  float2* __restrict__ pp) {
  __shared__ unsigned short As[2][2][128 * 64];
  __shared__ unsigned short Bs[2][2][128 * 64];
  const int tid = threadIdx.x;
  const int w = tid >> 6;
  const int l = tid & 63;
  const int wr = w >> 2;   // 0..1 (M half)
  const int wc = w & 3;    // 0..3 (N quarter)

  // T1: XCD-aware swizzle. grid = 1000 blocks, 1000 % 8 == 0.
  const int bid = blockIdx.x;
  const int cpx = gridDim.x >> 3;                 // 125
  const int swz = (bid & 7) * cpx + (bid >> 3);
  const int mt = swz & 7;                         // 8 M-tiles
  const int nt = swz >> 3;                        // 125 N-tiles

  const size_t Abase = (size_t)mt * 256 * HID;
  const size_t Bbase = (size_t)nt * 256 * HID;

  f32x4 acc[8][4] = {};

  const int r8 = l >> 3;
  const int scol = ((l & 7) ^ r8) << 3;  // swizzled source column (elements)

  auto stageA = [&](int half, int v) {
    const unsigned short* src = A + Abase + (size_t)half * 128 * HID + (size_t)v * 64 + scol;
#pragma unroll
    for (int i = 0; i < 2; ++i) {
      const int c = 2 * w + i;
      gload_lds16(src + (size_t)(c * 8 + r8) * HID, &As[v & 1][half][c * 512]);
    }
  };
  auto stageB = [&](int half, int v) {
    const unsigned short* src = B + Bbase + (size_t)half * 128 * HID + (size_t)v * 64 + scol;
#pragma unroll
    for (int i = 0; i < 2; ++i) {
      const int c = 2 * w + i;
      gload_lds16(src + (size_t)(c * 8 + r8) * HID, &Bs[v & 1][half][c * 512]);
    }
  };

  // prologue: tiles 0 and 1 (16 in flight); retire tile 0 (keep tile 1 flying)
  stageA(0, 0); stageA(1, 0); stageB(0, 0); stageB(1, 0);
  stageA(0, 1); stageA(1, 1); stageB(0, 1); stageB(1, 1);
  asm volatile("s_waitcnt vmcnt(8)" ::: "memory");
  __builtin_amdgcn_s_barrier();

  const int lr = l & 15;
  const int c0 = ((l >> 4) << 4) ^ ((lr & 7) << 4);  // byte col for kk=0
  const int c1 = c0 ^ 64;                            // byte col for kk=32
  const int brow = (wc & 1) * 64;                    // wave's N-row base in its B half

#pragma unroll 2
  for (int u = 0; u < NKT; ++u) {
    const int cur = u & 1;
    const char* Ah = (const char*)&As[cur][wr][0];
    const char* Bh = (const char*)&Bs[cur][wc >> 1][0];
    bf16x8 a0[8], a1[8], b0[4], b1[4];

    // ---- issue all 24 ds_reads ----
#pragma unroll
    for (int mf = 0; mf < 4; ++mf) {
      const int rb = (mf * 16 + lr) << 7;
      a0[2 * mf]     = *(const bf16x8*)(Ah + rb + c0);
      a0[2 * mf + 1] = *(const bf16x8*)(Ah + rb + c1);
    }
#pragma unroll
    for (int nf = 0; nf < 2; ++nf) {
      const int rb = (brow + nf * 16 + lr) << 7;
      b0[2 * nf]     = *(const bf16x8*)(Bh + rb + c0);
      b0[2 * nf + 1] = *(const bf16x8*)(Bh + rb + c1);
    }
#pragma unroll
    for (int mf = 0; mf < 4; ++mf) {
      const int rb = ((mf + 4) * 16 + lr) << 7;
      a1[2 * mf]     = *(const bf16x8*)(Ah + rb + c0);
      a1[2 * mf + 1] = *(const bf16x8*)(Ah + rb + c1);
    }
#pragma unroll
    for (int nf = 0; nf < 2; ++nf) {
      const int rb = (brow + (nf + 2) * 16 + lr) << 7;
      b1[2 * nf]     = *(const bf16x8*)(Bh + rb + c0);
      b1[2 * nf + 1] = *(const bf16x8*)(Bh + rb + c1);
    }

    __builtin_amdgcn_s_setprio(1);
    // q(0,0), q(1,0), q(1,1): 48 MFMA (compiler interleaves with auto lgkm waits)
#pragma unroll
    for (int mf = 0; mf < 4; ++mf)
#pragma unroll
      for (int nf = 0; nf < 2; ++nf) {
        acc[mf][nf] = __builtin_amdgcn_mfma_f32_16x16x32_bf16(a0[2 * mf], b0[2 * nf], acc[mf][nf], 0, 0, 0);
        acc[mf][nf] = __builtin_amdgcn_mfma_f32_16x16x32_bf16(a0[2 * mf + 1], b0[2 * nf + 1], acc[mf][nf], 0, 0, 0);
      }
#pragma unroll
    for (int mf = 0; mf < 4; ++mf)
#pragma unroll
      for (int nf = 0; nf < 2; ++nf) {
        acc[4 + mf][nf] = __builtin_amdgcn_mfma_f32_16x16x32_bf16(a1[2 * mf], b0[2 * nf], acc[4 + mf][nf], 0, 0, 0);
        acc[4 + mf][nf] = __builtin_amdgcn_mfma_f32_16x16x32_bf16(a1[2 * mf + 1], b0[2 * nf + 1], acc[4 + mf][nf], 0, 0, 0);
      }
#pragma unroll
    for (int mf = 0; mf < 4; ++mf)
#pragma unroll
      for (int nf = 0; nf < 2; ++nf) {
        acc[4 + mf][2 + nf] = __builtin_amdgcn_mfma_f32_16x16x32_bf16(a1[2 * mf], b1[2 * nf], acc[4 + mf][2 + nf], 0, 0, 0);
        acc[4 + mf][2 + nf] = __builtin_amdgcn_mfma_f32_16x16x32_bf16(a1[2 * mf + 1], b1[2 * nf + 1], acc[4 + mf][2 + nf], 0, 0, 0);
      }
    __builtin_amdgcn_s_setprio(0);

    // mid: all reads of buf cur drained chip-wide, then stage (u+2) into buf cur
    if (u + 2 < NKT) {
      asm volatile("s_waitcnt lgkmcnt(0)" ::: "memory");
      __builtin_amdgcn_s_barrier();
      stageA(0, u + 2); stageA(1, u + 2);
      stageB(0, u + 2); stageB(1, u + 2);
    }

    __builtin_amdgcn_s_setprio(1);
    // q(0,1): register-only (a0, b1 held) — covers stage-issue shadow
#pragma unroll
    for (int mf = 0; mf < 4; ++mf)
#pragma unroll
      for (int nf = 0; nf < 2; ++nf) {
        acc[mf][2 + nf] = __builtin_amdgcn_mfma_f32_16x16x32_bf16(a0[2 * mf], b1[2 * nf], acc[mf][2 + nf], 0, 0, 0);
        acc[mf][2 + nf] = __builtin_amdgcn_mfma_f32_16x16x32_bf16(a0[2 * mf + 1], b1[2 * nf + 1], acc[mf][2 + nf], 0, 0, 0);
      }
    __builtin_amdgcn_s_setprio(0);

    // end: counted vmcnt — retire stages(u+1) (issued ~1.5 tiles ago), keep (u+2)
    if (u + 1 < NKT) {
      if (u + 2 < NKT) {
        asm volatile("s_waitcnt vmcnt(8)" ::: "memory");
      } else {
        asm volatile("s_waitcnt vmcnt(0)" ::: "memory");  // u=62: only stages(63) in flight
      }
      __builtin_amdgcn_s_barrier();
    }
  }

  // ---- epilogue 1: fused per-row LSE over this block's 256 cols (bf16-rounded) ----
  __syncthreads();  // all K-loop LDS reads done; reuse As as reduction scratch
  float* red = (float*)&As[0][0][0];  // [256 rows][4 wc][2]
  const int lg = (l >> 4) * 4;
#pragma unroll
  for (int mf = 0; mf < 8; ++mf)
#pragma unroll
    for (int r = 0; r < 4; ++r) {
      float z[4];
#pragma unroll
      for (int nf = 0; nf < 4; ++nf) z[nf] = bf2f(f2bf(acc[mf][nf][r]));
      float vmax = fmaxf(fmaxf(z[0], z[1]), fmaxf(z[2], z[3]));
      float vsum = __expf(z[0] - vmax) + __expf(z[1] - vmax) +
                   __expf(z[2] - vmax) + __expf(z[3] - vmax);
#pragma unroll
      for (int off = 1; off < 16; off <<= 1)
        merge_ms(vmax, vsum, __shfl_xor(vmax, off), __shfl_xor(vsum, off));
      if (lr == 0) {
        const int rowl = wr * 128 + mf * 16 + lg + r;
        red[(rowl << 3) | (wc << 1)]     = vmax;
        red[(rowl << 3) | (wc << 1) | 1] = vsum;
      }
    }
  __syncthreads();
  if (tid < 256) {
    float m = red[(tid << 3)], s = red[(tid << 3) | 1];
#pragma unroll
    for (int i = 1; i < 4; ++i)
      merge_ms(m, s, red[(tid << 3) | (i << 1)], red[(tid << 3) | (i << 1) | 1]);
    pp[(size_t)(mt * 256 + tid) * NNT + nt] = make_float2(m, s);
  }

  // ---- epilogue 2: C write (bf16) ----
#pragma unroll
  for (int mf = 0; mf < 8; ++mf)
#pragma unroll
    for (int nf = 0; nf < 4; ++nf)
#pragma unroll
      for (int r = 0; r < 4; ++r) {
        const int row = mt * 256 + wr * 128 + mf * 16 + lg + r;
        const int col = nt * 256 + wc * 64 + nf * 16 + lr;
        C[(size_t)row * VOC + col] = f2bf(acc[mf][nf][r]);
      }
}

// ---------------- per-token JSD (single pass; LSE from GEMM partials) ----------------
__global__ __launch_bounds__(256) void jsd_kernel(const unsigned short* __restrict__ SL,
                                                  const unsigned short* __restrict__ TL,
                                                  const float2* __restrict__ ppS,
                                                  const float2* __restrict__ ppT,
                                                  float* __restrict__ partials) {
  const int t = blockIdx.x;
  const int tid = threadIdx.x;
  const unsigned short* srow = SL + (size_t)t * VOC;
  const unsigned short* trow = TL + (size_t)t * VOC;

  // merge the 125 per-tile LSE partials for S and T.
  // FINITE sentinel (-1e30f) for empty lanes: -INFINITY here gives
  // (-inf) - (-inf) = NaN inside merge_ms (round-8 bug).
  float ms = -1e30f, ss = 0.f, mt_ = -1e30f, st = 0.f;
  if (tid < NNT) {
    float2 vs = ppS[(size_t)t * NNT + tid];
    float2 vt = ppT[(size_t)t * NNT + tid];
    ms = vs.x; ss = vs.y; mt_ = vt.x; st = vt.y;
  }
#pragma unroll
  for (int off = 32; off > 0; off >>= 1) {
    float om = __shfl_xor(ms, off), os = __shfl_xor(ss, off);
    merge_ms(ms, ss, om, os);
    float omt = __shfl_xor(mt_, off), ost = __shfl_xor(st, off);
    merge_ms(mt_, st, omt, ost);
  }
  __shared__ float red[4][4];
  const int w = tid >> 6;
  if ((tid & 63) == 0) { red[w][0] = ms; red[w][1] = ss; red[w][2] = mt_; red[w][3] = st; }
  __syncthreads();
  float Ms = red[0][0], Ss = red[0][1], Mt = red[0][2], St = red[0][3];
#pragma unroll
  for (int i = 1; i < 4; ++i) {
    merge_ms(Ms, Ss, red[i][0], red[i][1]);
    merge_ms(Mt, St, red[i][2], red[i][3]);
  }
  const float logZs = Ms + __logf(Ss);
  const float logZt = Mt + __logf(St);

  // single pass: jsd = 0.5*[p*(lp-lm) + q*(lq-lm)], lm = log(0.5)+logaddexp(lp,lq)
  float acc = 0.f;
  for (int c = tid; c < VOC / 8; c += 256) {
    u16x8 vs = *(const u16x8*)(srow + c * 8);
    u16x8 vt = *(const u16x8*)(trow + c * 8);
#pragma unroll
    for (int j = 0; j < 8; ++j) {
      float lq = bf2f(vs[j]) - logZs;
      float lp = bf2f(vt[j]) - logZt;
      float mx = fmaxf(lp, lq);
      float d = fabsf(lp - lq);
      float lm = mx + __logf(1.f + __expf(-d)) - 0.69314718f;
      acc += __expf(lp) * (lp - lm) + __expf(lq) * (lq - lm);
    }
  }
  acc *= 0.5f;
#pragma unroll
  for (int off = 32; off > 0; off >>= 1) acc += __shfl_xor(acc, off);
  __shared__ float red2[4];
  if ((tid & 63) == 0) red2[w] = acc;
  __syncthreads();
  if (tid == 0) partials[t] = red2[0] + red2[1] + red2[2] + red2[3];
}

__global__ __launch_bounds__(256) void final_reduce(const float* __restrict__ partials,
                                                    float* __restrict__ out) {
  float a = 0.f;
  for (int i = threadIdx.x; i < TOK; i += 256) a += partials[i];
#pragma unroll
  for (int off = 32; off > 0; off >>= 1) a += __shfl_xor(a, off);
  __shared__ float red[4];
  const int w = threadIdx.x >> 6;
  if ((threadIdx.x & 63) == 0) red[w] = a;
  __syncthreads();
  if (threadIdx.x == 0) out[0] = (red[0] + red[1] + red[2] + red[3]) * (1.0f / TOK);
}

// ---------------- launch ----------------
extern "C" void kernel_launch(void* const* d_in, const int* in_sizes, int n_in,
                              void* d_out, int out_size, void* d_ws, size_t ws_size,
                              hipStream_t stream) {
  const float* sIn = (const float*)d_in[0];
  const float* tIn = (const float*)d_in[1];
  const float* sW  = (const float*)d_in[2];
  const float* tW  = (const float*)d_in[3];
  float* out = (float*)d_out;

  unsigned short* ws = (unsigned short*)d_ws;
  unsigned short* sA  = ws;                        // 2048*4096 bf16
  unsigned short* tA  = sA  + (long)TOK * HID;     // 2048*4096
  unsigned short* sWb = tA  + (long)TOK * HID;     // 32000*4096
  unsigned short* tWb = sWb + (long)VOC * HID;     // 32000*4096
  unsigned short* sL  = tWb + (long)VOC * HID;     // 2048*32000
  unsigned short* tL  = sL  + (long)TOK * VOC;     // 2048*32000
  float2* ppS = (float2*)(tL + (long)TOK * VOC);   // 2048*125 float2
  float2* ppT = ppS + (long)TOK * NNT;             // 2048*125 float2
  float* partials = (float*)(ppT + (long)TOK * NNT);

  cast_f32_bf16<<<2048, 256, 0, stream>>>(sIn, sA, (long)TOK * HID);
  cast_f32_bf16<<<2048, 256, 0, stream>>>(tIn, tA, (long)TOK * HID);
  cast_f32_bf16<<<2048, 256, 0, stream>>>(sW, sWb, (long)VOC * HID);
  cast_f32_bf16<<<2048, 256, 0, stream>>>(tW, tWb, (long)VOC * HID);

  const int nblk = (TOK / 256) * (VOC / 256);  // 8 * 125 = 1000
  gemm256<<<nblk, 512, 0, stream>>>(sA, sWb, sL, ppS);
  gemm256<<<nblk, 512, 0, stream>>>(tA, tWb, tL, ppT);

  jsd_kernel<<<TOK, 256, 0, stream>>>(sL, tL, ppS, ppT, partials);
  final_reduce<<<1, 256, 0, stream>>>(partials, out);
}

// Round 10
// 1283.418 us; speedup vs baseline: 2.6893x; 1.0395x over previous
//
#include <hip/hip_runtime.h>
#include <stdint.h>

#define TOK 2048
#define HID 4096
#define VOC 32000
#define NKT (HID / 64)  // 64 K-tiles of BK=64
#define NNT (VOC / 256) // 125 N-tiles

typedef __attribute__((ext_vector_type(4))) float f32x4;
typedef __attribute__((ext_vector_type(8))) short bf16x8;
typedef __attribute__((ext_vector_type(8))) unsigned short u16x8;

__device__ __forceinline__ float bf2f(unsigned short u) {
  return __uint_as_float(((unsigned int)u) << 16);
}
__device__ __forceinline__ unsigned short f2bf(float f) {
  unsigned int u = __float_as_uint(f);
  u += 0x7FFFu + ((u >> 16) & 1u);  // round-to-nearest-even
  return (unsigned short)(u >> 16);
}

// ---------------- cast f32 -> bf16 ----------------
__global__ __launch_bounds__(256) void cast_f32_bf16(const float* __restrict__ in,
                                                     unsigned short* __restrict__ out,
                                                     long n) {
  long i = ((long)blockIdx.x * 256 + threadIdx.x) * 4;
  const long stride = (long)gridDim.x * 256 * 4;
  for (; i < n; i += stride) {
    const float4 v = *(const float4*)(in + i);
    ushort4 o;
    o.x = f2bf(v.x); o.y = f2bf(v.y); o.z = f2bf(v.z); o.w = f2bf(v.w);
    *(ushort4*)(out + i) = o;
  }
}

// ---------------- async global -> LDS (16B/lane) ----------------
__device__ __forceinline__ void gload_lds16(const void* g, void* l) {
  __builtin_amdgcn_global_load_lds(
      (const __attribute__((address_space(1))) unsigned int*)(uintptr_t)g,
      (__attribute__((address_space(3))) unsigned int*)(uintptr_t)l,
      16, 0, 0);
}

// NOTE: never merge two -INFINITY entries: -inf - -inf = NaN. Empty slots use
// the finite sentinel -1e30f (exp underflows to exactly 0 -> identity merge).
__device__ __forceinline__ void merge_ms(float& m, float& s, float om, float os) {
  float nm = fmaxf(m, om);
  s = s * __expf(m - nm) + os * __expf(om - nm);
  m = nm;
}

// ---------------- 256x256 bf16 GEMM (round-3 schedule) + fused row-LSE epilogue ----
// C[M,N] = A[M,K] * B[N,K]^T, both bf16 (weights pre-cast).
// 8 waves (2M x 4N), BK=64, LDS 2dbuf x 2half x [128][64] for A and B (128 KiB).
// Swizzle: byte ^= ((row&7)<<4) (pre-swizzled global source, same XOR on ds_read).
// Measured-best K-loop (r3=450us vs r7=467 vs r9=560): ds_reads | stageB(u+1)
// [issue overlaps 48-MFMA cluster] | q00,q10,q11 | lgkm0+bar | stageA(u+2) |
// q01 (reg-only) | vmcnt(4) retires A(u+1)+B(u+1), keeps A(u+2) | bar.
__global__ __launch_bounds__(512, 2) void gemm256(const unsigned short* __restrict__ A,
                                                  const unsigned short* __restrict__ B,
                                                  unsigned short* __restrict__ C,
                                                  float2* __restrict__ pp) {
  __shared__ unsigned short As[2][2][128 * 64];
  __shared__ unsigned short Bs[2][2][128 * 64];
  const int tid = threadIdx.x;
  const int w = tid >> 6;
  const int l = tid & 63;
  const int wr = w >> 2;   // 0..1 (M half)
  const int wc = w & 3;    // 0..3 (N quarter)

  // T1: XCD-aware swizzle. grid = 1000 blocks, 1000 % 8 == 0.
  const int bid = blockIdx.x;
  const int cpx = gridDim.x >> 3;                 // 125
  const int swz = (bid & 7) * cpx + (bid >> 3);
  const int mt = swz & 7;                         // 8 M-tiles
  const int nt = swz >> 3;                        // 125 N-tiles

  const size_t Abase = (size_t)mt * 256 * HID;
  const size_t Bbase = (size_t)nt * 256 * HID;

  f32x4 acc[8][4] = {};

  const int r8 = l >> 3;
  const int scol = ((l & 7) ^ r8) << 3;  // swizzled source column (elements)

  auto stageA = [&](int half, int v) {
    const unsigned short* src = A + Abase + (size_t)half * 128 * HID + (size_t)v * 64 + scol;
#pragma unroll
    for (int i = 0; i < 2; ++i) {
      const int c = 2 * w + i;
      gload_lds16(src + (size_t)(c * 8 + r8) * HID, &As[v & 1][half][c * 512]);
    }
  };
  auto stageB = [&](int half, int v) {
    const unsigned short* src = B + Bbase + (size_t)half * 128 * HID + (size_t)v * 64 + scol;
#pragma unroll
    for (int i = 0; i < 2; ++i) {
      const int c = 2 * w + i;
      gload_lds16(src + (size_t)(c * 8 + r8) * HID, &Bs[v & 1][half][c * 512]);
    }
  };

  // prologue: tile0 all halves + tile1 A halves; retire tile0's 8 (keep A(1) in flight)
  stageA(0, 0); stageA(1, 0); stageB(0, 0); stageB(1, 0);
  stageA(0, 1); stageA(1, 1);
  asm volatile("s_waitcnt vmcnt(4)" ::: "memory");
  __builtin_amdgcn_s_barrier();

  const int lr = l & 15;
  const int c0 = ((l >> 4) << 4) ^ ((lr & 7) << 4);  // byte col for kk=0
  const int c1 = c0 ^ 64;                            // byte col for kk=32
  const int brow = (wc & 1) * 64;                    // wave's N-row base in its B half

#pragma unroll 2
  for (int u = 0; u < NKT; ++u) {
    const int cur = u & 1;
    const char* Ah = (const char*)&As[cur][wr][0];
    const char* Bh = (const char*)&Bs[cur][wc >> 1][0];
    bf16x8 a0[8], a1[8], b0[4], b1[4];

    // ---- issue all 24 ds_reads (compiler schedules + counted auto-lgkmcnt) ----
#pragma unroll
    for (int mf = 0; mf < 4; ++mf) {
      const int rb = (mf * 16 + lr) << 7;
      a0[2 * mf]     = *(const bf16x8*)(Ah + rb + c0);
      a0[2 * mf + 1] = *(const bf16x8*)(Ah + rb + c1);
    }
#pragma unroll
    for (int nf = 0; nf < 2; ++nf) {
      const int rb = (brow + nf * 16 + lr) << 7;
      b0[2 * nf]     = *(const bf16x8*)(Bh + rb + c0);
      b0[2 * nf + 1] = *(const bf16x8*)(Bh + rb + c1);
    }
#pragma unroll
    for (int mf = 0; mf < 4; ++mf) {
      const int rb = ((mf + 4) * 16 + lr) << 7;
      a1[2 * mf]     = *(const bf16x8*)(Ah + rb + c0);
      a1[2 * mf + 1] = *(const bf16x8*)(Ah + rb + c1);
    }
#pragma unroll
    for (int nf = 0; nf < 2; ++nf) {
      const int rb = (brow + (nf + 2) * 16 + lr) << 7;
      b1[2 * nf]     = *(const bf16x8*)(Bh + rb + c0);
      b1[2 * nf + 1] = *(const bf16x8*)(Bh + rb + c1);
    }

    // stage B(u+1) into buf cur^1 — issue overlaps the 48-MFMA cluster
    if (u + 1 < NKT) { stageB(0, u + 1); stageB(1, u + 1); }

    __builtin_amdgcn_s_setprio(1);
    // q(0,0), q(1,0), q(1,1): 48 MFMA
#pragma unroll
    for (int mf = 0; mf < 4; ++mf)
#pragma unroll
      for (int nf = 0; nf < 2; ++nf) {
        acc[mf][nf] = __builtin_amdgcn_mfma_f32_16x16x32_bf16(a0[2 * mf], b0[2 * nf], acc[mf][nf], 0, 0, 0);
        acc[mf][nf] = __builtin_amdgcn_mfma_f32_16x16x32_bf16(a0[2 * mf + 1], b0[2 * nf + 1], acc[mf][nf], 0, 0, 0);
      }
#pragma unroll
    for (int mf = 0; mf < 4; ++mf)
#pragma unroll
      for (int nf = 0; nf < 2; ++nf) {
        acc[4 + mf][nf] = __builtin_amdgcn_mfma_f32_16x16x32_bf16(a1[2 * mf], b0[2 * nf], acc[4 + mf][nf], 0, 0, 0);
        acc[4 + mf][nf] = __builtin_amdgcn_mfma_f32_16x16x32_bf16(a1[2 * mf + 1], b0[2 * nf + 1], acc[4 + mf][nf], 0, 0, 0);
      }
#pragma unroll
    for (int mf = 0; mf < 4; ++mf)
#pragma unroll
      for (int nf = 0; nf < 2; ++nf) {
        acc[4 + mf][2 + nf] = __builtin_amdgcn_mfma_f32_16x16x32_bf16(a1[2 * mf], b1[2 * nf], acc[4 + mf][2 + nf], 0, 0, 0);
        acc[4 + mf][2 + nf] = __builtin_amdgcn_mfma_f32_16x16x32_bf16(a1[2 * mf + 1], b1[2 * nf + 1], acc[4 + mf][2 + nf], 0, 0, 0);
      }
    __builtin_amdgcn_s_setprio(0);

    // all reads of this tile's buffers drained chip-wide before stageA(u+2)
    // (writes As[cur]) can be issued by any wave
    asm volatile("s_waitcnt lgkmcnt(0)" ::: "memory");
    __builtin_amdgcn_s_barrier();

    if (u + 2 < NKT) { stageA(0, u + 2); stageA(1, u + 2); }

    __builtin_amdgcn_s_setprio(1);
    // q(0,1): register-only (a0, b1 held) — covers stage-issue + vmcnt shadow
#pragma unroll
    for (int mf = 0; mf < 4; ++mf)
#pragma unroll
      for (int nf = 0; nf < 2; ++nf) {
        acc[mf][2 + nf] = __builtin_amdgcn_mfma_f32_16x16x32_bf16(a0[2 * mf], b1[2 * nf], acc[mf][2 + nf], 0, 0, 0);
        acc[mf][2 + nf] = __builtin_amdgcn_mfma_f32_16x16x32_bf16(a0[2 * mf + 1], b1[2 * nf + 1], acc[mf][2 + nf], 0, 0, 0);
      }
    __builtin_amdgcn_s_setprio(0);

    if (u + 2 < NKT) {
      asm volatile("s_waitcnt vmcnt(4)" ::: "memory");  // retire A(u+1)+B(u+1), keep A(u+2)
      __builtin_amdgcn_s_barrier();
    } else if (u + 1 < NKT) {
      asm volatile("s_waitcnt vmcnt(0)" ::: "memory");  // u=62: drain A(63)+B(63)
      __builtin_amdgcn_s_barrier();
    }
  }

  // ---- epilogue 1: fused per-row LSE over this block's 256 cols (bf16-rounded) ----
  __syncthreads();  // all K-loop LDS reads done; reuse As as reduction scratch
  float* red = (float*)&As[0][0][0];  // [256 rows][4 wc][2]
  const int lg = (l >> 4) * 4;
#pragma unroll
  for (int mf = 0; mf < 8; ++mf)
#pragma unroll
    for (int r = 0; r < 4; ++r) {
      float z[4];
#pragma unroll
      for (int nf = 0; nf < 4; ++nf) z[nf] = bf2f(f2bf(acc[mf][nf][r]));
      float vmax = fmaxf(fmaxf(z[0], z[1]), fmaxf(z[2], z[3]));
      float vsum = __expf(z[0] - vmax) + __expf(z[1] - vmax) +
                   __expf(z[2] - vmax) + __expf(z[3] - vmax);
#pragma unroll
      for (int off = 1; off < 16; off <<= 1)
        merge_ms(vmax, vsum, __shfl_xor(vmax, off), __shfl_xor(vsum, off));
      if (lr == 0) {
        const int rowl = wr * 128 + mf * 16 + lg + r;
        red[(rowl << 3) | (wc << 1)]     = vmax;
        red[(rowl << 3) | (wc << 1) | 1] = vsum;
      }
    }
  __syncthreads();
  if (tid < 256) {
    float m = red[(tid << 3)], s = red[(tid << 3) | 1];
#pragma unroll
    for (int i = 1; i < 4; ++i)
      merge_ms(m, s, red[(tid << 3) | (i << 1)], red[(tid << 3) | (i << 1) | 1]);
    pp[(size_t)(mt * 256 + tid) * NNT + nt] = make_float2(m, s);
  }

  // ---- epilogue 2: C write (bf16) ----
#pragma unroll
  for (int mf = 0; mf < 8; ++mf)
#pragma unroll
    for (int nf = 0; nf < 4; ++nf)
#pragma unroll
      for (int r = 0; r < 4; ++r) {
        const int row = mt * 256 + wr * 128 + mf * 16 + lg + r;
        const int col = nt * 256 + wc * 64 + nf * 16 + lr;
        C[(size_t)row * VOC + col] = f2bf(acc[mf][nf][r]);
      }
}

// ---------------- per-token JSD (single pass; LSE from GEMM partials) ----------------
__global__ __launch_bounds__(256) void jsd_kernel(const unsigned short* __restrict__ SL,
                                                  const unsigned short* __restrict__ TL,
                                                  const float2* __restrict__ ppS,
                                                  const float2* __restrict__ ppT,
                                                  float* __restrict__ partials) {
  const int t = blockIdx.x;
  const int tid = threadIdx.x;
  const unsigned short* srow = SL + (size_t)t * VOC;
  const unsigned short* trow = TL + (size_t)t * VOC;

  // merge the 125 per-tile LSE partials (finite sentinel for empty lanes)
  float ms = -1e30f, ss = 0.f, mt_ = -1e30f, st = 0.f;
  if (tid < NNT) {
    float2 vs = ppS[(size_t)t * NNT + tid];
    float2 vt = ppT[(size_t)t * NNT + tid];
    ms = vs.x; ss = vs.y; mt_ = vt.x; st = vt.y;
  }
#pragma unroll
  for (int off = 32; off > 0; off >>= 1) {
    float om = __shfl_xor(ms, off), os = __shfl_xor(ss, off);
    merge_ms(ms, ss, om, os);
    float omt = __shfl_xor(mt_, off), ost = __shfl_xor(st, off);
    merge_ms(mt_, st, omt, ost);
  }
  __shared__ float red[4][4];
  const int w = tid >> 6;
  if ((tid & 63) == 0) { red[w][0] = ms; red[w][1] = ss; red[w][2] = mt_; red[w][3] = st; }
  __syncthreads();
  float Ms = red[0][0], Ss = red[0][1], Mt = red[0][2], St = red[0][3];
#pragma unroll
  for (int i = 1; i < 4; ++i) {
    merge_ms(Ms, Ss, red[i][0], red[i][1]);
    merge_ms(Mt, St, red[i][2], red[i][3]);
  }
  const float logZs = Ms + __logf(Ss);
  const float logZt = Mt + __logf(St);

  // single pass: jsd = 0.5*[p*(lp-lm) + q*(lq-lm)], lm = log(0.5)+logaddexp(lp,lq)
  float acc = 0.f;
  for (int c = tid; c < VOC / 8; c += 256) {
    u16x8 vs = *(const u16x8*)(srow + c * 8);
    u16x8 vt = *(const u16x8*)(trow + c * 8);
#pragma unroll
    for (int j = 0; j < 8; ++j) {
      float lq = bf2f(vs[j]) - logZs;
      float lp = bf2f(vt[j]) - logZt;
      float mx = fmaxf(lp, lq);
      float d = fabsf(lp - lq);
      float lm = mx + __logf(1.f + __expf(-d)) - 0.69314718f;
      acc += __expf(lp) * (lp - lm) + __expf(lq) * (lq - lm);
    }
  }
  acc *= 0.5f;
#pragma unroll
  for (int off = 32; off > 0; off >>= 1) acc += __shfl_xor(acc, off);
  __shared__ float red2[4];
  if ((tid & 63) == 0) red2[w] = acc;
  __syncthreads();
  if (tid == 0) partials[t] = red2[0] + red2[1] + red2[2] + red2[3];
}

__global__ __launch_bounds__(256) void final_reduce(const float* __restrict__ partials,
                                                    float* __restrict__ out) {
  float a = 0.f;
  for (int i = threadIdx.x; i < TOK; i += 256) a += partials[i];
#pragma unroll
  for (int off = 32; off > 0; off >>= 1) a += __shfl_xor(a, off);
  __shared__ float red[4];
  const int w = threadIdx.x >> 6;
  if ((threadIdx.x & 63) == 0) red[w] = a;
  __syncthreads();
  if (threadIdx.x == 0) out[0] = (red[0] + red[1] + red[2] + red[3]) * (1.0f / TOK);
}

// ---------------- launch ----------------
extern "C" void kernel_launch(void* const* d_in, const int* in_sizes, int n_in,
                              void* d_out, int out_size, void* d_ws, size_t ws_size,
                              hipStream_t stream) {
  const float* sIn = (const float*)d_in[0];
  const float* tIn = (const float*)d_in[1];
  const float* sW  = (const float*)d_in[2];
  const float* tW  = (const float*)d_in[3];
  float* out = (float*)d_out;

  unsigned short* ws = (unsigned short*)d_ws;
  unsigned short* sA  = ws;                        // 2048*4096 bf16
  unsigned short* tA  = sA  + (long)TOK * HID;     // 2048*4096
  unsigned short* sWb = tA  + (long)TOK * HID;     // 32000*4096
  unsigned short* tWb = sWb + (long)VOC * HID;     // 32000*4096
  unsigned short* sL  = tWb + (long)VOC * HID;     // 2048*32000
  unsigned short* tL  = sL  + (long)TOK * VOC;     // 2048*32000
  float2* ppS = (float2*)(tL + (long)TOK * VOC);   // 2048*125 float2
  float2* ppT = ppS + (long)TOK * NNT;             // 2048*125 float2
  float* partials = (float*)(ppT + (long)TOK * NNT);

  cast_f32_bf16<<<2048, 256, 0, stream>>>(sIn, sA, (long)TOK * HID);
  cast_f32_bf16<<<2048, 256, 0, stream>>>(tIn, tA, (long)TOK * HID);
  cast_f32_bf16<<<2048, 256, 0, stream>>>(sW, sWb, (long)VOC * HID);
  cast_f32_bf16<<<2048, 256, 0, stream>>>(tW, tWb, (long)VOC * HID);

  const int nblk = (TOK / 256) * (VOC / 256);  // 8 * 125 = 1000
  gemm256<<<nblk, 512, 0, stream>>>(sA, sWb, sL, ppS);
  gemm256<<<nblk, 512, 0, stream>>>(tA, tWb, tL, ppT);

  jsd_kernel<<<TOK, 256, 0, stream>>>(sL, tL, ppS, ppT, partials);
  final_reduce<<<1, 256, 0, stream>>>(partials, out);
}

// Round 11
// 1251.018 us; speedup vs baseline: 2.7590x; 1.0259x over previous
//
#include <hip/hip_runtime.h>
#include <stdint.h>

#define TOK 2048
#define HID 4096
#define VOC 32000
#define NKT (HID / 64)  // 64 K-tiles of BK=64
#define NNT (VOC / 256) // 125 N-tiles
#define MREF 16.0f      // fixed LSE reference: exp(z-16) safe for |z| << 70

typedef __attribute__((ext_vector_type(4))) float f32x4;
typedef __attribute__((ext_vector_type(8))) short bf16x8;
typedef __attribute__((ext_vector_type(8))) unsigned short u16x8;

__device__ __forceinline__ float bf2f(unsigned short u) {
  return __uint_as_float(((unsigned int)u) << 16);
}
__device__ __forceinline__ unsigned short f2bf(float f) {
  unsigned int u = __float_as_uint(f);
  u += 0x7FFFu + ((u >> 16) & 1u);  // round-to-nearest-even
  return (unsigned short)(u >> 16);
}

// ---------------- cast f32 -> bf16, 8 elems/thread/iter (16B stores) ----------------
__global__ __launch_bounds__(256) void cast_f32_bf16(const float* __restrict__ in,
                                                     unsigned short* __restrict__ out,
                                                     long n) {
  long i = ((long)blockIdx.x * 256 + threadIdx.x) * 8;
  const long stride = (long)gridDim.x * 256 * 8;
  for (; i < n; i += stride) {
    const float4 v0 = *(const float4*)(in + i);
    const float4 v1 = *(const float4*)(in + i + 4);
    union { ushort s[8]; uint4 u; } o;
    o.s[0] = f2bf(v0.x); o.s[1] = f2bf(v0.y); o.s[2] = f2bf(v0.z); o.s[3] = f2bf(v0.w);
    o.s[4] = f2bf(v1.x); o.s[5] = f2bf(v1.y); o.s[6] = f2bf(v1.z); o.s[7] = f2bf(v1.w);
    *(uint4*)(out + i) = o.u;
  }
}

// ---------------- async global -> LDS (16B/lane) ----------------
__device__ __forceinline__ void gload_lds16(const void* g, void* l) {
  __builtin_amdgcn_global_load_lds(
      (const __attribute__((address_space(1))) unsigned int*)(uintptr_t)g,
      (__attribute__((address_space(3))) unsigned int*)(uintptr_t)l,
      16, 0, 0);
}

// NOTE: never merge two -INFINITY entries: -inf - -inf = NaN. Empty slots use
// the finite sentinel -1e30f (exp underflows to exactly 0 -> identity merge).
__device__ __forceinline__ void merge_ms(float& m, float& s, float om, float os) {
  float nm = fmaxf(m, om);
  s = s * __expf(m - nm) + os * __expf(om - nm);
  m = nm;
}

// ---------------- 256x256 bf16 GEMM (round-3 schedule) + fixed-ref LSE epilogue ----
// C[M,N] = A[M,K] * B[N,K]^T, both bf16 (weights pre-cast).
// 8 waves (2M x 4N), BK=64, LDS 2dbuf x 2half x [128][64] for A and B (128 KiB).
// Swizzle: byte ^= ((row&7)<<4) (pre-swizzled global source, same XOR on ds_read).
// K-loop identical to r10 (measured-best): ds_reads | stageB(u+1) | q00,q10,q11 |
// lgkm0+bar | stageA(u+2) | q01 (reg-only) | vmcnt(4)+bar.
// Epilogue: pp[row][nt] = (MREF, sum exp(z-MREF)) -- no max tracking (logits
// ~N(0,1); exp(z-16) cannot over/underflow), so all reduces are pure adds.
__global__ __launch_bounds__(512, 2) void gemm256(const unsigned short* __restrict__ A,
                                                  const unsigned short* __restrict__ B,
                                                  unsigned short* __restrict__ C,
                                                  float2* __restrict__ pp) {
  __shared__ unsigned short As[2][2][128 * 64];
  __shared__ unsigned short Bs[2][2][128 * 64];
  const int tid = threadIdx.x;
  const int w = tid >> 6;
  const int l = tid & 63;
  const int wr = w >> 2;   // 0..1 (M half)
  const int wc = w & 3;    // 0..3 (N quarter)

  // T1: XCD-aware swizzle. grid = 1000 blocks, 1000 % 8 == 0.
  const int bid = blockIdx.x;
  const int cpx = gridDim.x >> 3;                 // 125
  const int swz = (bid & 7) * cpx + (bid >> 3);
  const int mt = swz & 7;                         // 8 M-tiles
  const int nt = swz >> 3;                        // 125 N-tiles

  const size_t Abase = (size_t)mt * 256 * HID;
  const size_t Bbase = (size_t)nt * 256 * HID;

  f32x4 acc[8][4] = {};

  const int r8 = l >> 3;
  const int scol = ((l & 7) ^ r8) << 3;  // swizzled source column (elements)

  auto stageA = [&](int half, int v) {
    const unsigned short* src = A + Abase + (size_t)half * 128 * HID + (size_t)v * 64 + scol;
#pragma unroll
    for (int i = 0; i < 2; ++i) {
      const int c = 2 * w + i;
      gload_lds16(src + (size_t)(c * 8 + r8) * HID, &As[v & 1][half][c * 512]);
    }
  };
  auto stageB = [&](int half, int v) {
    const unsigned short* src = B + Bbase + (size_t)half * 128 * HID + (size_t)v * 64 + scol;
#pragma unroll
    for (int i = 0; i < 2; ++i) {
      const int c = 2 * w + i;
      gload_lds16(src + (size_t)(c * 8 + r8) * HID, &Bs[v & 1][half][c * 512]);
    }
  };

  // prologue: tile0 all halves + tile1 A halves; retire tile0's 8 (keep A(1) in flight)
  stageA(0, 0); stageA(1, 0); stageB(0, 0); stageB(1, 0);
  stageA(0, 1); stageA(1, 1);
  asm volatile("s_waitcnt vmcnt(4)" ::: "memory");
  __builtin_amdgcn_s_barrier();

  const int lr = l & 15;
  const int c0 = ((l >> 4) << 4) ^ ((lr & 7) << 4);  // byte col for kk=0
  const int c1 = c0 ^ 64;                            // byte col for kk=32
  const int brow = (wc & 1) * 64;                    // wave's N-row base in its B half

#pragma unroll 2
  for (int u = 0; u < NKT; ++u) {
    const int cur = u & 1;
    const char* Ah = (const char*)&As[cur][wr][0];
    const char* Bh = (const char*)&Bs[cur][wc >> 1][0];
    bf16x8 a0[8], a1[8], b0[4], b1[4];

    // ---- issue all 24 ds_reads (compiler schedules + counted auto-lgkmcnt) ----
#pragma unroll
    for (int mf = 0; mf < 4; ++mf) {
      const int rb = (mf * 16 + lr) << 7;
      a0[2 * mf]     = *(const bf16x8*)(Ah + rb + c0);
      a0[2 * mf + 1] = *(const bf16x8*)(Ah + rb + c1);
    }
#pragma unroll
    for (int nf = 0; nf < 2; ++nf) {
      const int rb = (brow + nf * 16 + lr) << 7;
      b0[2 * nf]     = *(const bf16x8*)(Bh + rb + c0);
      b0[2 * nf + 1] = *(const bf16x8*)(Bh + rb + c1);
    }
#pragma unroll
    for (int mf = 0; mf < 4; ++mf) {
      const int rb = ((mf + 4) * 16 + lr) << 7;
      a1[2 * mf]     = *(const bf16x8*)(Ah + rb + c0);
      a1[2 * mf + 1] = *(const bf16x8*)(Ah + rb + c1);
    }
#pragma unroll
    for (int nf = 0; nf < 2; ++nf) {
      const int rb = (brow + (nf + 2) * 16 + lr) << 7;
      b1[2 * nf]     = *(const bf16x8*)(Bh + rb + c0);
      b1[2 * nf + 1] = *(const bf16x8*)(Bh + rb + c1);
    }

    // stage B(u+1) into buf cur^1 — issue overlaps the 48-MFMA cluster
    if (u + 1 < NKT) { stageB(0, u + 1); stageB(1, u + 1); }

    __builtin_amdgcn_s_setprio(1);
    // q(0,0), q(1,0), q(1,1): 48 MFMA
#pragma unroll
    for (int mf = 0; mf < 4; ++mf)
#pragma unroll
      for (int nf = 0; nf < 2; ++nf) {
        acc[mf][nf] = __builtin_amdgcn_mfma_f32_16x16x32_bf16(a0[2 * mf], b0[2 * nf], acc[mf][nf], 0, 0, 0);
        acc[mf][nf] = __builtin_amdgcn_mfma_f32_16x16x32_bf16(a0[2 * mf + 1], b0[2 * nf + 1], acc[mf][nf], 0, 0, 0);
      }
#pragma unroll
    for (int mf = 0; mf < 4; ++mf)
#pragma unroll
      for (int nf = 0; nf < 2; ++nf) {
        acc[4 + mf][nf] = __builtin_amdgcn_mfma_f32_16x16x32_bf16(a1[2 * mf], b0[2 * nf], acc[4 + mf][nf], 0, 0, 0);
        acc[4 + mf][nf] = __builtin_amdgcn_mfma_f32_16x16x32_bf16(a1[2 * mf + 1], b0[2 * nf + 1], acc[4 + mf][nf], 0, 0, 0);
      }
#pragma unroll
    for (int mf = 0; mf < 4; ++mf)
#pragma unroll
      for (int nf = 0; nf < 2; ++nf) {
        acc[4 + mf][2 + nf] = __builtin_amdgcn_mfma_f32_16x16x32_bf16(a1[2 * mf], b1[2 * nf], acc[4 + mf][2 + nf], 0, 0, 0);
        acc[4 + mf][2 + nf] = __builtin_amdgcn_mfma_f32_16x16x32_bf16(a1[2 * mf + 1], b1[2 * nf + 1], acc[4 + mf][2 + nf], 0, 0, 0);
      }
    __builtin_amdgcn_s_setprio(0);

    // all reads of this tile's buffers drained chip-wide before stageA(u+2)
    asm volatile("s_waitcnt lgkmcnt(0)" ::: "memory");
    __builtin_amdgcn_s_barrier();

    if (u + 2 < NKT) { stageA(0, u + 2); stageA(1, u + 2); }

    __builtin_amdgcn_s_setprio(1);
    // q(0,1): register-only (a0, b1 held) — covers stage-issue + vmcnt shadow
#pragma unroll
    for (int mf = 0; mf < 4; ++mf)
#pragma unroll
      for (int nf = 0; nf < 2; ++nf) {
        acc[mf][2 + nf] = __builtin_amdgcn_mfma_f32_16x16x32_bf16(a0[2 * mf], b1[2 * nf], acc[mf][2 + nf], 0, 0, 0);
        acc[mf][2 + nf] = __builtin_amdgcn_mfma_f32_16x16x32_bf16(a0[2 * mf + 1], b1[2 * nf + 1], acc[mf][2 + nf], 0, 0, 0);
      }
    __builtin_amdgcn_s_setprio(0);

    if (u + 2 < NKT) {
      asm volatile("s_waitcnt vmcnt(4)" ::: "memory");  // retire A(u+1)+B(u+1), keep A(u+2)
      __builtin_amdgcn_s_barrier();
    } else if (u + 1 < NKT) {
      asm volatile("s_waitcnt vmcnt(0)" ::: "memory");  // u=62: drain A(63)+B(63)
      __builtin_amdgcn_s_barrier();
    }
  }

  // ---- epilogue: C write + fixed-ref row-sum of exp(z-MREF), fused ----
  __syncthreads();  // all K-loop LDS reads done; reuse As as reduction scratch
  float* red = (float*)&As[0][0][0];  // [256 rows][stride 5] (pad -> conflict-free)
  const int lg = (l >> 4) * 4;
#pragma unroll
  for (int mf = 0; mf < 8; ++mf)
#pragma unroll
    for (int r = 0; r < 4; ++r) {
      const int rowl = wr * 128 + mf * 16 + lg + r;
      const int row = mt * 256 + rowl;
      float vsum = 0.f;
#pragma unroll
      for (int nf = 0; nf < 4; ++nf) {
        const unsigned short cb = f2bf(acc[mf][nf][r]);
        C[(size_t)row * VOC + nt * 256 + wc * 64 + nf * 16 + lr] = cb;
        vsum += __expf(bf2f(cb) - MREF);
      }
#pragma unroll
      for (int off = 1; off < 16; off <<= 1) vsum += __shfl_xor(vsum, off);
      if (lr == 0) red[rowl * 5 + wc] = vsum;
    }
  __syncthreads();
  if (tid < 256) {
    const float s = red[tid * 5] + red[tid * 5 + 1] + red[tid * 5 + 2] + red[tid * 5 + 3];
    pp[(size_t)(mt * 256 + tid) * NNT + nt] = make_float2(MREF, s);
  }
}

// ---------------- per-token JSD (single pass; LSE from GEMM partials) ----------------
__global__ __launch_bounds__(256) void jsd_kernel(const unsigned short* __restrict__ SL,
                                                  const unsigned short* __restrict__ TL,
                                                  const float2* __restrict__ ppS,
                                                  const float2* __restrict__ ppT,
                                                  float* __restrict__ partials) {
  const int t = blockIdx.x;
  const int tid = threadIdx.x;
  const unsigned short* srow = SL + (size_t)t * VOC;
  const unsigned short* trow = TL + (size_t)t * VOC;

  // merge the 125 per-tile LSE partials (finite sentinel for empty lanes)
  float ms = -1e30f, ss = 0.f, mt_ = -1e30f, st = 0.f;
  if (tid < NNT) {
    float2 vs = ppS[(size_t)t * NNT + tid];
    float2 vt = ppT[(size_t)t * NNT + tid];
    ms = vs.x; ss = vs.y; mt_ = vt.x; st = vt.y;
  }
#pragma unroll
  for (int off = 32; off > 0; off >>= 1) {
    float om = __shfl_xor(ms, off), os = __shfl_xor(ss, off);
    merge_ms(ms, ss, om, os);
    float omt = __shfl_xor(mt_, off), ost = __shfl_xor(st, off);
    merge_ms(mt_, st, omt, ost);
  }
  __shared__ float red[4][4];
  const int w = tid >> 6;
  if ((tid & 63) == 0) { red[w][0] = ms; red[w][1] = ss; red[w][2] = mt_; red[w][3] = st; }
  __syncthreads();
  float Ms = red[0][0], Ss = red[0][1], Mt = red[0][2], St = red[0][3];
#pragma unroll
  for (int i = 1; i < 4; ++i) {
    merge_ms(Ms, Ss, red[i][0], red[i][1]);
    merge_ms(Mt, St, red[i][2], red[i][3]);
  }
  const float logZs = Ms + __logf(Ss);
  const float logZt = Mt + __logf(St);

  // single pass: jsd = 0.5*[p*(lp-lm) + q*(lq-lm)], lm = log(0.5)+logaddexp(lp,lq)
  float acc = 0.f;
  for (int c = tid; c < VOC / 8; c += 256) {
    u16x8 vs = *(const u16x8*)(srow + c * 8);
    u16x8 vt = *(const u16x8*)(trow + c * 8);
#pragma unroll
    for (int j = 0; j < 8; ++j) {
      float lq = bf2f(vs[j]) - logZs;
      float lp = bf2f(vt[j]) - logZt;
      float mx = fmaxf(lp, lq);
      float d = fabsf(lp - lq);
      float lm = mx + __logf(1.f + __expf(-d)) - 0.69314718f;
      acc += __expf(lp) * (lp - lm) + __expf(lq) * (lq - lm);
    }
  }
  acc *= 0.5f;
#pragma unroll
  for (int off = 32; off > 0; off >>= 1) acc += __shfl_xor(acc, off);
  __shared__ float red2[4];
  if ((tid & 63) == 0) red2[w] = acc;
  __syncthreads();
  if (tid == 0) partials[t] = red2[0] + red2[1] + red2[2] + red2[3];
}

__global__ __launch_bounds__(256) void final_reduce(const float* __restrict__ partials,
                                                    float* __restrict__ out) {
  float a = 0.f;
  for (int i = threadIdx.x; i < TOK; i += 256) a += partials[i];
#pragma unroll
  for (int off = 32; off > 0; off >>= 1) a += __shfl_xor(a, off);
  __shared__ float red[4];
  const int w = threadIdx.x >> 6;
  if ((threadIdx.x & 63) == 0) red[w] = a;
  __syncthreads();
  if (threadIdx.x == 0) out[0] = (red[0] + red[1] + red[2] + red[3]) * (1.0f / TOK);
}

// ---------------- launch ----------------
extern "C" void kernel_launch(void* const* d_in, const int* in_sizes, int n_in,
                              void* d_out, int out_size, void* d_ws, size_t ws_size,
                              hipStream_t stream) {
  const float* sIn = (const float*)d_in[0];
  const float* tIn = (const float*)d_in[1];
  const float* sW  = (const float*)d_in[2];
  const float* tW  = (const float*)d_in[3];
  float* out = (float*)d_out;

  unsigned short* ws = (unsigned short*)d_ws;
  unsigned short* sA  = ws;                        // 2048*4096 bf16
  unsigned short* tA  = sA  + (long)TOK * HID;     // 2048*4096
  unsigned short* sWb = tA  + (long)TOK * HID;     // 32000*4096
  unsigned short* tWb = sWb + (long)VOC * HID;     // 32000*4096
  unsigned short* sL  = tWb + (long)VOC * HID;     // 2048*32000
  unsigned short* tL  = sL  + (long)TOK * VOC;     // 2048*32000
  float2* ppS = (float2*)(tL + (long)TOK * VOC);   // 2048*125 float2
  float2* ppT = ppS + (long)TOK * NNT;             // 2048*125 float2
  float* partials = (float*)(ppT + (long)TOK * NNT);

  cast_f32_bf16<<<2048, 256, 0, stream>>>(sIn, sA, (long)TOK * HID);
  cast_f32_bf16<<<2048, 256, 0, stream>>>(tIn, tA, (long)TOK * HID);
  cast_f32_bf16<<<2048, 256, 0, stream>>>(sW, sWb, (long)VOC * HID);
  cast_f32_bf16<<<2048, 256, 0, stream>>>(tW, tWb, (long)VOC * HID);

  const int nblk = (TOK / 256) * (VOC / 256);  // 8 * 125 = 1000
  gemm256<<<nblk, 512, 0, stream>>>(sA, sWb, sL, ppS);
  gemm256<<<nblk, 512, 0, stream>>>(tA, tWb, tL, ppT);

  jsd_kernel<<<TOK, 256, 0, stream>>>(sL, tL, ppS, ppT, partials);
  final_reduce<<<1, 256, 0, stream>>>(partials, out);
}

// Round 12
// 1245.790 us; speedup vs baseline: 2.7706x; 1.0042x over previous
//
#include <hip/hip_runtime.h>
#include <stdint.h>

#define TOK 2048
#define HID 4096
#define VOC 32000
#define NKT (HID / 64)  // 64 K-tiles of BK=64
#define NNT (VOC / 256) // 125 N-tiles
#define MREF 16.0f      // fixed LSE reference: exp(z-16) safe for |z| << 70

typedef __attribute__((ext_vector_type(4))) float f32x4;
typedef __attribute__((ext_vector_type(8))) short bf16x8;
typedef __attribute__((ext_vector_type(8))) unsigned short u16x8;

__device__ __forceinline__ float bf2f(unsigned short u) {
  return __uint_as_float(((unsigned int)u) << 16);
}
__device__ __forceinline__ unsigned short f2bf(float f) {
  unsigned int u = __float_as_uint(f);
  u += 0x7FFFu + ((u >> 16) & 1u);  // round-to-nearest-even
  return (unsigned short)(u >> 16);
}

// ---------------- all four casts in one launch (4 grid-stride regions) ----------------
__device__ __forceinline__ void cast8(const float* __restrict__ in,
                                      unsigned short* __restrict__ out) {
  const float4 v0 = *(const float4*)(in);
  const float4 v1 = *(const float4*)(in + 4);
  union { ushort s[8]; uint4 u; } o;
  o.s[0] = f2bf(v0.x); o.s[1] = f2bf(v0.y); o.s[2] = f2bf(v0.z); o.s[3] = f2bf(v0.w);
  o.s[4] = f2bf(v1.x); o.s[5] = f2bf(v1.y); o.s[6] = f2bf(v1.z); o.s[7] = f2bf(v1.w);
  *(uint4*)(out) = o.u;
}

__global__ __launch_bounds__(256) void cast_all(const float* __restrict__ a, unsigned short* __restrict__ oa, long na,
                                                const float* __restrict__ b, unsigned short* __restrict__ ob, long nb,
                                                const float* __restrict__ c, unsigned short* __restrict__ oc, long nc,
                                                const float* __restrict__ d, unsigned short* __restrict__ od, long nd) {
  const long base = ((long)blockIdx.x * 256 + threadIdx.x) * 8;
  const long stride = (long)gridDim.x * 256 * 8;
  for (long i = base; i < na; i += stride) cast8(a + i, oa + i);
  for (long i = base; i < nb; i += stride) cast8(b + i, ob + i);
  for (long i = base; i < nc; i += stride) cast8(c + i, oc + i);
  for (long i = base; i < nd; i += stride) cast8(d + i, od + i);
}

// ---------------- async global -> LDS (16B/lane) ----------------
__device__ __forceinline__ void gload_lds16(const void* g, void* l) {
  __builtin_amdgcn_global_load_lds(
      (const __attribute__((address_space(1))) unsigned int*)(uintptr_t)g,
      (__attribute__((address_space(3))) unsigned int*)(uintptr_t)l,
      16, 0, 0);
}

// ---------------- dual 256x256 bf16 GEMM (one dispatch) + fixed-ref LSE epilogue ----
// Blocks 0..999 (after XCD swizzle) -> student, 1000..1999 -> teacher.
// K-loop byte-identical to r10/r11 measured-best: ds_reads | stageB(u+1) |
// q00,q10,q11 | lgkm0+bar | stageA(u+2) | q01 (reg-only) | vmcnt(4)+bar.
// Epilogue: C write + pp[row][nt] = (MREF, sum exp(z-MREF)) — pure-add reduces.
__global__ __launch_bounds__(512, 2) void gemm256(const unsigned short* __restrict__ A0,
                                                  const unsigned short* __restrict__ B0,
                                                  unsigned short* __restrict__ C0,
                                                  float2* __restrict__ pp0,
                                                  const unsigned short* __restrict__ A1,
                                                  const unsigned short* __restrict__ B1,
                                                  unsigned short* __restrict__ C1,
                                                  float2* __restrict__ pp1) {
  __shared__ unsigned short As[2][2][128 * 64];
  __shared__ unsigned short Bs[2][2][128 * 64];
  const int tid = threadIdx.x;
  const int w = tid >> 6;
  const int l = tid & 63;
  const int wr = w >> 2;   // 0..1 (M half)
  const int wc = w & 3;    // 0..3 (N quarter)

  // T1: XCD swizzle over the merged 2000-block grid (2000 % 8 == 0).
  // XCDs 0-3 -> student tiles, XCDs 4-7 -> teacher tiles; per-XCD contiguous nt.
  const int bid = blockIdx.x;
  const int cpx = gridDim.x >> 3;                 // 250
  int swz = (bid & 7) * cpx + (bid >> 3);
  const int which = swz >= (TOK / 256) * NNT;     // >= 1000 -> teacher
  if (which) swz -= (TOK / 256) * NNT;
  const int mt = swz & 7;                         // 8 M-tiles
  const int nt = swz >> 3;                        // 125 N-tiles

  const unsigned short* __restrict__ A = which ? A1 : A0;
  const unsigned short* __restrict__ B = which ? B1 : B0;
  unsigned short* __restrict__ C = which ? C1 : C0;
  float2* __restrict__ pp = which ? pp1 : pp0;

  const size_t Abase = (size_t)mt * 256 * HID;
  const size_t Bbase = (size_t)nt * 256 * HID;

  f32x4 acc[8][4] = {};

  const int r8 = l >> 3;
  const int scol = ((l & 7) ^ r8) << 3;  // swizzled source column (elements)

  auto stageA = [&](int half, int v) {
    const unsigned short* src = A + Abase + (size_t)half * 128 * HID + (size_t)v * 64 + scol;
#pragma unroll
    for (int i = 0; i < 2; ++i) {
      const int c = 2 * w + i;
      gload_lds16(src + (size_t)(c * 8 + r8) * HID, &As[v & 1][half][c * 512]);
    }
  };
  auto stageB = [&](int half, int v) {
    const unsigned short* src = B + Bbase + (size_t)half * 128 * HID + (size_t)v * 64 + scol;
#pragma unroll
    for (int i = 0; i < 2; ++i) {
      const int c = 2 * w + i;
      gload_lds16(src + (size_t)(c * 8 + r8) * HID, &Bs[v & 1][half][c * 512]);
    }
  };

  // prologue: tile0 all halves + tile1 A halves; retire tile0's 8 (keep A(1) in flight)
  stageA(0, 0); stageA(1, 0); stageB(0, 0); stageB(1, 0);
  stageA(0, 1); stageA(1, 1);
  asm volatile("s_waitcnt vmcnt(4)" ::: "memory");
  __builtin_amdgcn_s_barrier();

  const int lr = l & 15;
  const int c0 = ((l >> 4) << 4) ^ ((lr & 7) << 4);  // byte col for kk=0
  const int c1 = c0 ^ 64;                            // byte col for kk=32
  const int brow = (wc & 1) * 64;                    // wave's N-row base in its B half

#pragma unroll 2
  for (int u = 0; u < NKT; ++u) {
    const int cur = u & 1;
    const char* Ah = (const char*)&As[cur][wr][0];
    const char* Bh = (const char*)&Bs[cur][wc >> 1][0];
    bf16x8 a0[8], a1[8], b0[4], b1[4];

    // ---- issue all 24 ds_reads (compiler schedules + counted auto-lgkmcnt) ----
#pragma unroll
    for (int mf = 0; mf < 4; ++mf) {
      const int rb = (mf * 16 + lr) << 7;
      a0[2 * mf]     = *(const bf16x8*)(Ah + rb + c0);
      a0[2 * mf + 1] = *(const bf16x8*)(Ah + rb + c1);
    }
#pragma unroll
    for (int nf = 0; nf < 2; ++nf) {
      const int rb = (brow + nf * 16 + lr) << 7;
      b0[2 * nf]     = *(const bf16x8*)(Bh + rb + c0);
      b0[2 * nf + 1] = *(const bf16x8*)(Bh + rb + c1);
    }
#pragma unroll
    for (int mf = 0; mf < 4; ++mf) {
      const int rb = ((mf + 4) * 16 + lr) << 7;
      a1[2 * mf]     = *(const bf16x8*)(Ah + rb + c0);
      a1[2 * mf + 1] = *(const bf16x8*)(Ah + rb + c1);
    }
#pragma unroll
    for (int nf = 0; nf < 2; ++nf) {
      const int rb = (brow + (nf + 2) * 16 + lr) << 7;
      b1[2 * nf]     = *(const bf16x8*)(Bh + rb + c0);
      b1[2 * nf + 1] = *(const bf16x8*)(Bh + rb + c1);
    }

    // stage B(u+1) into buf cur^1 — issue overlaps the 48-MFMA cluster
    if (u + 1 < NKT) { stageB(0, u + 1); stageB(1, u + 1); }

    __builtin_amdgcn_s_setprio(1);
    // q(0,0), q(1,0), q(1,1): 48 MFMA
#pragma unroll
    for (int mf = 0; mf < 4; ++mf)
#pragma unroll
      for (int nf = 0; nf < 2; ++nf) {
        acc[mf][nf] = __builtin_amdgcn_mfma_f32_16x16x32_bf16(a0[2 * mf], b0[2 * nf], acc[mf][nf], 0, 0, 0);
        acc[mf][nf] = __builtin_amdgcn_mfma_f32_16x16x32_bf16(a0[2 * mf + 1], b0[2 * nf + 1], acc[mf][nf], 0, 0, 0);
      }
#pragma unroll
    for (int mf = 0; mf < 4; ++mf)
#pragma unroll
      for (int nf = 0; nf < 2; ++nf) {
        acc[4 + mf][nf] = __builtin_amdgcn_mfma_f32_16x16x32_bf16(a1[2 * mf], b0[2 * nf], acc[4 + mf][nf], 0, 0, 0);
        acc[4 + mf][nf] = __builtin_amdgcn_mfma_f32_16x16x32_bf16(a1[2 * mf + 1], b0[2 * nf + 1], acc[4 + mf][nf], 0, 0, 0);
      }
#pragma unroll
    for (int mf = 0; mf < 4; ++mf)
#pragma unroll
      for (int nf = 0; nf < 2; ++nf) {
        acc[4 + mf][2 + nf] = __builtin_amdgcn_mfma_f32_16x16x32_bf16(a1[2 * mf], b1[2 * nf], acc[4 + mf][2 + nf], 0, 0, 0);
        acc[4 + mf][2 + nf] = __builtin_amdgcn_mfma_f32_16x16x32_bf16(a1[2 * mf + 1], b1[2 * nf + 1], acc[4 + mf][2 + nf], 0, 0, 0);
      }
    __builtin_amdgcn_s_setprio(0);

    // all reads of this tile's buffers drained chip-wide before stageA(u+2)
    asm volatile("s_waitcnt lgkmcnt(0)" ::: "memory");
    __builtin_amdgcn_s_barrier();

    if (u + 2 < NKT) { stageA(0, u + 2); stageA(1, u + 2); }

    __builtin_amdgcn_s_setprio(1);
    // q(0,1): register-only (a0, b1 held) — covers stage-issue + vmcnt shadow
#pragma unroll
    for (int mf = 0; mf < 4; ++mf)
#pragma unroll
      for (int nf = 0; nf < 2; ++nf) {
        acc[mf][2 + nf] = __builtin_amdgcn_mfma_f32_16x16x32_bf16(a0[2 * mf], b1[2 * nf], acc[mf][2 + nf], 0, 0, 0);
        acc[mf][2 + nf] = __builtin_amdgcn_mfma_f32_16x16x32_bf16(a0[2 * mf + 1], b1[2 * nf + 1], acc[mf][2 + nf], 0, 0, 0);
      }
    __builtin_amdgcn_s_setprio(0);

    if (u + 2 < NKT) {
      asm volatile("s_waitcnt vmcnt(4)" ::: "memory");  // retire A(u+1)+B(u+1), keep A(u+2)
      __builtin_amdgcn_s_barrier();
    } else if (u + 1 < NKT) {
      asm volatile("s_waitcnt vmcnt(0)" ::: "memory");  // u=62: drain A(63)+B(63)
      __builtin_amdgcn_s_barrier();
    }
  }

  // ---- epilogue: C write + fixed-ref row-sum of exp(z-MREF), fused ----
  __syncthreads();  // all K-loop LDS reads done; reuse As as reduction scratch
  float* red = (float*)&As[0][0][0];  // [256 rows][stride 5] (pad -> conflict-free)
  const int lg = (l >> 4) * 4;
#pragma unroll
  for (int mf = 0; mf < 8; ++mf)
#pragma unroll
    for (int r = 0; r < 4; ++r) {
      const int rowl = wr * 128 + mf * 16 + lg + r;
      const int row = mt * 256 + rowl;
      float vsum = 0.f;
#pragma unroll
      for (int nf = 0; nf < 4; ++nf) {
        const unsigned short cb = f2bf(acc[mf][nf][r]);
        C[(size_t)row * VOC + nt * 256 + wc * 64 + nf * 16 + lr] = cb;
        vsum += __expf(bf2f(cb) - MREF);
      }
#pragma unroll
      for (int off = 1; off < 16; off <<= 1) vsum += __shfl_xor(vsum, off);
      if (lr == 0) red[rowl * 5 + wc] = vsum;
    }
  __syncthreads();
  if (tid < 256) {
    const float s = red[tid * 5] + red[tid * 5 + 1] + red[tid * 5 + 2] + red[tid * 5 + 3];
    pp[(size_t)(mt * 256 + tid) * NNT + nt] = make_float2(MREF, s);
  }
}

// ---------------- per-token JSD (single pass; LSE partials are pure sums) ----------------
__global__ __launch_bounds__(256) void jsd_kernel(const unsigned short* __restrict__ SL,
                                                  const unsigned short* __restrict__ TL,
                                                  const float2* __restrict__ ppS,
                                                  const float2* __restrict__ ppT,
                                                  float* __restrict__ partials) {
  const int t = blockIdx.x;
  const int tid = threadIdx.x;
  const unsigned short* srow = SL + (size_t)t * VOC;
  const unsigned short* trow = TL + (size_t)t * VOC;

  // all partial maxima are MREF -> exact additive merge, no exp chains
  float ss = 0.f, st = 0.f;
  if (tid < NNT) {
    ss = ppS[(size_t)t * NNT + tid].y;
    st = ppT[(size_t)t * NNT + tid].y;
  }
#pragma unroll
  for (int off = 32; off > 0; off >>= 1) {
    ss += __shfl_xor(ss, off);
    st += __shfl_xor(st, off);
  }
  __shared__ float red[4][2];
  const int w = tid >> 6;
  if ((tid & 63) == 0) { red[w][0] = ss; red[w][1] = st; }
  __syncthreads();
  const float Ss = red[0][0] + red[1][0] + red[2][0] + red[3][0];
  const float St = red[0][1] + red[1][1] + red[2][1] + red[3][1];
  const float logZs = MREF + __logf(Ss);
  const float logZt = MREF + __logf(St);

  // single pass: jsd = 0.5*[p*(lp-lm) + q*(lq-lm)], lm = log(0.5)+logaddexp(lp,lq)
  float acc = 0.f;
  for (int c = tid; c < VOC / 8; c += 256) {
    u16x8 vs = *(const u16x8*)(srow + c * 8);
    u16x8 vt = *(const u16x8*)(trow + c * 8);
#pragma unroll
    for (int j = 0; j < 8; ++j) {
      float lq = bf2f(vs[j]) - logZs;
      float lp = bf2f(vt[j]) - logZt;
      float mx = fmaxf(lp, lq);
      float d = fabsf(lp - lq);
      float lm = mx + __logf(1.f + __expf(-d)) - 0.69314718f;
      acc += __expf(lp) * (lp - lm) + __expf(lq) * (lq - lm);
    }
  }
  acc *= 0.5f;
#pragma unroll
  for (int off = 32; off > 0; off >>= 1) acc += __shfl_xor(acc, off);
  __shared__ float red2[4];
  if ((tid & 63) == 0) red2[w] = acc;
  __syncthreads();
  if (tid == 0) partials[t] = red2[0] + red2[1] + red2[2] + red2[3];
}

__global__ __launch_bounds__(256) void final_reduce(const float* __restrict__ partials,
                                                    float* __restrict__ out) {
  float a = 0.f;
  for (int i = threadIdx.x; i < TOK; i += 256) a += partials[i];
#pragma unroll
  for (int off = 32; off > 0; off >>= 1) a += __shfl_xor(a, off);
  __shared__ float red[4];
  const int w = threadIdx.x >> 6;
  if ((threadIdx.x & 63) == 0) red[w] = a;
  __syncthreads();
  if (threadIdx.x == 0) out[0] = (red[0] + red[1] + red[2] + red[3]) * (1.0f / TOK);
}

// ---------------- launch ----------------
extern "C" void kernel_launch(void* const* d_in, const int* in_sizes, int n_in,
                              void* d_out, int out_size, void* d_ws, size_t ws_size,
                              hipStream_t stream) {
  const float* sIn = (const float*)d_in[0];
  const float* tIn = (const float*)d_in[1];
  const float* sW  = (const float*)d_in[2];
  const float* tW  = (const float*)d_in[3];
  float* out = (float*)d_out;

  unsigned short* ws = (unsigned short*)d_ws;
  unsigned short* sA  = ws;                        // 2048*4096 bf16
  unsigned short* tA  = sA  + (long)TOK * HID;     // 2048*4096
  unsigned short* sWb = tA  + (long)TOK * HID;     // 32000*4096
  unsigned short* tWb = sWb + (long)VOC * HID;     // 32000*4096
  unsigned short* sL  = tWb + (long)VOC * HID;     // 2048*32000
  unsigned short* tL  = sL  + (long)TOK * VOC;     // 2048*32000
  float2* ppS = (float2*)(tL + (long)TOK * VOC);   // 2048*125 float2
  float2* ppT = ppS + (long)TOK * NNT;             // 2048*125 float2
  float* partials = (float*)(ppT + (long)TOK * NNT);

  cast_all<<<2048, 256, 0, stream>>>(sIn, sA, (long)TOK * HID,
                                     tIn, tA, (long)TOK * HID,
                                     sW, sWb, (long)VOC * HID,
                                     tW, tWb, (long)VOC * HID);

  const int nblk = 2 * (TOK / 256) * (VOC / 256);  // 2000: student + teacher
  gemm256<<<nblk, 512, 0, stream>>>(sA, sWb, sL, ppS, tA, tWb, tL, ppT);

  jsd_kernel<<<TOK, 256, 0, stream>>>(sL, tL, ppS, ppT, partials);
  final_reduce<<<1, 256, 0, stream>>>(partials, out);
}